// Round 3
// baseline (282.711 us; speedup 1.0000x reference)
//
#include <hip/hip_runtime.h>
#include <cstddef>

static constexpr int TT = 64;    // decoder steps
static constexpr int BB = 8;     // batch
static constexpr int SS = 512;   // source length
static constexpr int HH = 512;   // hidden

typedef __attribute__((ext_vector_type(8))) short bf16x8;
typedef __attribute__((ext_vector_type(4))) float f32x4;

__device__ __forceinline__ float fast_tanh(float x) {
  float e = __expf(2.0f * x);
  return 1.0f - 2.0f * __builtin_amdgcn_rcpf(e + 1.0f);
}
__device__ __forceinline__ unsigned short f2bf(float f) {
  unsigned u = __float_as_uint(f);
  return (unsigned short)((u + 0x7FFFu + ((u >> 16) & 1u)) >> 16);   // RNE
}
__device__ __forceinline__ float bflo(unsigned u) { return __uint_as_float(u << 16); }
__device__ __forceinline__ float bfhi(unsigned u) { return __uint_as_float(u & 0xffff0000u); }

// ---------------------------------------------------------------------------
// k_prep — all preprocessing, vectorized (float4/ushort4):
//  [0,2048):     encpb = bf16(tanh(enc + cov*wcov)), 2 bs-rows/block
//  [2048,2304):  dec pack -> concatb right half, 2 m-rows/block
//  [2304,3328):  weight transposes Wq,Wc,Wo (32x32 tiles -> WT[n][k] bf16)
// ---------------------------------------------------------------------------
__global__ __launch_bounds__(256)
void k_prep(const float* __restrict__ enc, const float* __restrict__ cov,
            const float* __restrict__ wcov, const float* __restrict__ dec,
            const float* __restrict__ Wq, const float* __restrict__ Wc,
            const float* __restrict__ Wo,
            unsigned short* __restrict__ encpb, unsigned short* __restrict__ concatb,
            unsigned short* __restrict__ WqT, unsigned short* __restrict__ WcT,
            unsigned short* __restrict__ WoT) {
  __shared__ float tile[32][33];
  const int blk = blockIdx.x, tid = threadIdx.x;

  if (blk < 2048) {
    const int r = tid >> 7, c = (tid & 127) * 4;
    const int bs = blk * 2 + r;
    const int s = bs & 511, b = bs >> 9;
    const float4 ev = *(const float4*)(enc + (size_t)(s * BB + b) * HH + c);
    const float cv = cov[bs];
    const float4 wv = *(const float4*)(wcov + c);
    ushort4 o;
    o.x = f2bf(fast_tanh(ev.x + cv * wv.x));
    o.y = f2bf(fast_tanh(ev.y + cv * wv.y));
    o.z = f2bf(fast_tanh(ev.z + cv * wv.z));
    o.w = f2bf(fast_tanh(ev.w + cv * wv.w));
    *(ushort4*)(encpb + (size_t)bs * HH + c) = o;
  } else if (blk < 2304) {
    const int r = tid >> 7, c = (tid & 127) * 4;
    const int m = (blk - 2048) * 2 + r, t = m & 63, b = m >> 6;   // m = b*64+t
    const float4 dv = *(const float4*)(dec + (size_t)(t * BB + b) * HH + c);
    ushort4 o;
    o.x = f2bf(dv.x); o.y = f2bf(dv.y); o.z = f2bf(dv.z); o.w = f2bf(dv.w);
    *(ushort4*)(concatb + (size_t)m * 1024 + 512 + c) = o;
  } else {
    int l = blk - 2304;
    const float* W; unsigned short* WT; int KT;
    if (l < 256)      { W = Wq; WT = WqT; KT = 512; }
    else if (l < 512) { W = Wc; WT = WcT; KT = 512; l -= 256; }
    else              { W = Wo; WT = WoT; KT = 1024; l -= 512; }
    const int n0 = (l & 15) * 32, k0 = (l >> 4) * 32;
    const int r = tid >> 3, c4 = (tid & 7) * 4;
    const float4 w = *(const float4*)(W + (size_t)(k0 + r) * 512 + n0 + c4);
    tile[r][c4 + 0] = w.x; tile[r][c4 + 1] = w.y;
    tile[r][c4 + 2] = w.z; tile[r][c4 + 3] = w.w;
    __syncthreads();
    unsigned short* o = WT + (size_t)(n0 + r) * KT + k0 + c4;
#pragma unroll
    for (int i = 0; i < 4; ++i) o[i] = f2bf(tile[c4 + i][r]);
  }
}

// ---------------------------------------------------------------------------
// 64x64 bf16 MFMA tile over K range. 256 thr / 4 waves.
// C/D layout: col=lane&15, row=(lane>>4)*4+reg (verified earlier).
// ---------------------------------------------------------------------------
template<int LDA, int LDB>
__device__ __forceinline__ void gemm_tile(const unsigned short* __restrict__ A,
                                          const unsigned short* __restrict__ BT,
                                          int m0, int n0, int kbeg, int kend,
                                          unsigned short (*As)[72],
                                          unsigned short (*Bs)[72],
                                          f32x4 acc[4]) {
  const int tid = threadIdx.x, w = tid >> 6, lane = tid & 63;
  const int lr = tid >> 2, lk = (tid & 3) * 16;
  const int fm = w * 16 + (lane & 15), fk = (lane >> 4) * 8;
  for (int k0 = kbeg; k0 < kend; k0 += 64) {
    const uint4* ga = (const uint4*)(A + (size_t)(m0 + lr) * LDA + k0 + lk);
    const uint4* gb = (const uint4*)(BT + (size_t)(n0 + lr) * LDB + k0 + lk);
    uint4 a0 = ga[0], a1 = ga[1], b0 = gb[0], b1 = gb[1];
    *(uint4*)&As[lr][lk] = a0;  *(uint4*)&As[lr][lk + 8] = a1;
    *(uint4*)&Bs[lr][lk] = b0;  *(uint4*)&Bs[lr][lk + 8] = b1;
    __syncthreads();
#pragma unroll
    for (int ks = 0; ks < 2; ++ks) {
      bf16x8 af = *(const bf16x8*)&As[fm][ks * 32 + fk];
#pragma unroll
      for (int j = 0; j < 4; ++j) {
        bf16x8 bf = *(const bf16x8*)&Bs[j * 16 + (lane & 15)][ks * 32 + fk];
        acc[j] = __builtin_amdgcn_mfma_f32_16x16x32_bf16(af, bf, acc[j], 0, 0, 0);
      }
    }
    __syncthreads();
  }
}

// ---------------------------------------------------------------------------
// k_gemm12 — three GEMM jobs in ONE launch (640 blocks):
//  g <  64: Ea1 (fp32) = exp(2*clamp(dec@Wq + bq, +-10.5))
//  g < 576: Ea2b (BF16) = exp(2*clamp(encp@Wc, +-10.5))   <- halves L2 stream
//  g < 640: attn_h base = dec@Wo_bot + bo (scattered [T,B,H]); k_attn adds c@Wo_top
// clamp +-10.5: pair-product (Ea1*Ea2+1)^2 <= 2.9e36 finite; tanh(10.5)=1-1.5e-9.
// ---------------------------------------------------------------------------
__global__ __launch_bounds__(256)
void k_gemm12(const unsigned short* __restrict__ concatb,
              const unsigned short* __restrict__ encpb,
              const unsigned short* __restrict__ WqT,
              const unsigned short* __restrict__ WcT,
              const unsigned short* __restrict__ WoT,
              const float* __restrict__ bq, const float* __restrict__ bo,
              float* __restrict__ Ea1, unsigned short* __restrict__ Ea2b,
              float* __restrict__ attn_h) {
  __shared__ unsigned short As[64][72];
  __shared__ unsigned short Bs[64][72];
  const int g = blockIdx.x, tid = threadIdx.x;
  const int w = tid >> 6, lane = tid & 63;
  const int col = lane & 15, rq = lane >> 4;

  if (g < 64) {                        // a1
    const int m0 = (g >> 3) * 64, n0 = (g & 7) * 64;
    f32x4 acc[4] = {};
    gemm_tile<1024, 512>(concatb + 512, WqT, m0, n0, 0, 512, As, Bs, acc);
#pragma unroll
    for (int j = 0; j < 4; ++j) {
      const int n = n0 + j * 16 + col;
      const float bv = bq[n];
#pragma unroll
      for (int r = 0; r < 4; ++r) {
        const int m = m0 + w * 16 + rq * 4 + r;
        float val = fminf(fmaxf(acc[j][r] + bv, -10.5f), 10.5f);
        Ea1[(size_t)m * 512 + n] = __expf(2.0f * val);
      }
    }
  } else if (g < 576) {                // a2 -> bf16
    const int u = g - 64;
    const int m0 = (u >> 3) * 64, n0 = (u & 7) * 64;
    f32x4 acc[4] = {};
    gemm_tile<512, 512>(encpb, WcT, m0, n0, 0, 512, As, Bs, acc);
#pragma unroll
    for (int j = 0; j < 4; ++j) {
      const int n = n0 + j * 16 + col;
#pragma unroll
      for (int r = 0; r < 4; ++r) {
        const int m = m0 + w * 16 + rq * 4 + r;
        float val = fminf(fmaxf(acc[j][r], -10.5f), 10.5f);
        Ea2b[(size_t)m * 512 + n] = f2bf(__expf(2.0f * val));
      }
    }
  } else {                             // attn_h base = dec@Wo_bot + bo
    const int u = g - 576;
    const int m0 = (u >> 3) * 64, n0 = (u & 7) * 64;
    f32x4 acc[4] = {};
    gemm_tile<1024, 1024>(concatb, WoT, m0, n0, 512, 1024, As, Bs, acc);
#pragma unroll
    for (int j = 0; j < 4; ++j) {
      const int n = n0 + j * 16 + col;
      const float bv = bo[n];
#pragma unroll
      for (int r = 0; r < 4; ++r) {
        const int m = m0 + w * 16 + rq * 4 + r;
        const int bi = m >> 6, t = m & 63;
        attn_h[(size_t)(t * BB + bi) * 512 + n] = acc[j][r] + bv;
      }
    }
  }
}

// ---------------------------------------------------------------------------
// k_attn — scores + softmax + context + fused output projection.
// 256 blocks (b, t-pair), 1024 thr.
// Scores (pair-rcp, bf16 Ea2): sc = -(sum_h 2 v_h/(Ea1*Ea2+1)).
// Projection: wave-cooperative — 8 lanes per n-row reading CONTIGUOUS 16B
// chunks (16 cache lines/instr, the coalescing floor), both t per weight
// load (halves WoT traffic), 8-lane shfl reduce. Replaces the round-2
// one-thread-per-row layout whose 1KB-strided lanes cost 64 lines/instr
// (~27 us of L1 request serialization -> the 61.5 us k_attn regression).
// ---------------------------------------------------------------------------
__global__ __launch_bounds__(1024)
void k_attn(const float* __restrict__ Ea1, const unsigned short* __restrict__ Ea2b,
            const float* __restrict__ v, const unsigned short* __restrict__ encpb,
            const unsigned short* __restrict__ WoT,
            float* __restrict__ align_out, float* __restrict__ attn_h) {
  __shared__ __align__(16) char smem[24640];
  float (*sc)[512]   = (float(*)[512])smem;            // [2][512] scores->align
  float (*ea1s)[512] = (float(*)[512])(smem + 4096);   // [2][512] (scores phase)
  float* v2s         = (float*)(smem + 12288);         // [512]    (scores phase)
  float2* part       = (float2*)(smem + 4096);         // [2][4][256] (ctx phase)
  float (*red)[8]    = (float(*)[8])(smem + 20480);    // [2][8]
  float* cs          = (float*)(smem + 20544);         // [2][512] f32 context

  const int g = blockIdx.x, tid = threadIdx.x;
  const int b = g & 7, t0 = (g >> 3) * 2;              // XCD-affine b
  const int wv = tid >> 6, lane = tid & 63;
  const int hq = lane & 3, sl = lane >> 2;

  if (tid < 512) {
    ea1s[0][tid] = Ea1[(size_t)(b * TT + t0) * HH + tid];
    ea1s[1][tid] = Ea1[(size_t)(b * TT + t0 + 1) * HH + tid];
  } else {
    v2s[tid - 512] = 2.0f * v[tid - 512];
  }
  __syncthreads();

  // ---- scores: 16 waves x 32 s, one pass; 32-h chunks (8 bf16/lane-load) ----
  const int s0 = wv * 32 + sl;                         // and s0+16
  {
    const unsigned short* e2r0 = Ea2b + (size_t)(b * SS + s0) * HH;
    const unsigned short* e2r1 = e2r0 + (size_t)16 * HH;
    float acc[2][2] = {};
#define PAIR(E1a, E2a, Va, E1b, E2b, Vb, A)                                  \
    {                                                                        \
      const float x1 = fmaf(E1a, E2a, 1.0f), x2 = fmaf(E1b, E2b, 1.0f);      \
      const float rr = __builtin_amdgcn_rcpf(x1 * x2);                       \
      const float nn = fmaf(Va, x2, Vb * x1);                                \
      A = fmaf(nn, rr, A);                                                   \
    }
#pragma unroll 4
    for (int it = 0; it < 16; ++it) {
      const int h = it * 32 + hq * 8;
      const uint4 u0 = *(const uint4*)(e2r0 + h);
      const uint4 u1 = *(const uint4*)(e2r1 + h);
      const float4 va = *(const float4*)&v2s[h];
      const float4 vb = *(const float4*)&v2s[h + 4];
      float4 e1a[2], e1b[2];
      e1a[0] = *(const float4*)&ea1s[0][h]; e1b[0] = *(const float4*)&ea1s[0][h + 4];
      e1a[1] = *(const float4*)&ea1s[1][h]; e1b[1] = *(const float4*)&ea1s[1][h + 4];
#pragma unroll
      for (int i = 0; i < 2; ++i) {
        PAIR(e1a[i].x, bflo(u0.x), va.x, e1a[i].y, bfhi(u0.x), va.y, acc[i][0]);
        PAIR(e1a[i].z, bflo(u0.y), va.z, e1a[i].w, bfhi(u0.y), va.w, acc[i][0]);
        PAIR(e1b[i].x, bflo(u0.z), vb.x, e1b[i].y, bfhi(u0.z), vb.y, acc[i][0]);
        PAIR(e1b[i].z, bflo(u0.w), vb.z, e1b[i].w, bfhi(u0.w), vb.w, acc[i][0]);
        PAIR(e1a[i].x, bflo(u1.x), va.x, e1a[i].y, bfhi(u1.x), va.y, acc[i][1]);
        PAIR(e1a[i].z, bflo(u1.y), va.z, e1a[i].w, bfhi(u1.y), va.w, acc[i][1]);
        PAIR(e1b[i].x, bflo(u1.z), vb.x, e1b[i].y, bfhi(u1.z), vb.y, acc[i][1]);
        PAIR(e1b[i].z, bflo(u1.w), vb.z, e1b[i].w, bfhi(u1.w), vb.w, acc[i][1]);
      }
    }
#undef PAIR
#pragma unroll
    for (int i = 0; i < 2; ++i)
#pragma unroll
      for (int j = 0; j < 2; ++j) {
        acc[i][j] += __shfl_xor(acc[i][j], 1);
        acc[i][j] += __shfl_xor(acc[i][j], 2);
      }
    if (hq == 0) {
      sc[0][s0] = -acc[0][0]; sc[0][s0 + 16] = -acc[0][1];
      sc[1][s0] = -acc[1][0]; sc[1][s0 + 16] = -acc[1][1];
    }
  }
  __syncthreads();

  // ---- softmax over s (threads < 512 own s=tid; all threads hit barriers) --
  float x0 = 0.f, x1 = 0.f, e0 = 0.f, e1 = 0.f;
  if (tid < 512) {
    x0 = sc[0][tid]; x1 = sc[1][tid];
    float m0 = x0, m1 = x1;
#pragma unroll
    for (int off = 32; off; off >>= 1) {
      m0 = fmaxf(m0, __shfl_xor(m0, off));
      m1 = fmaxf(m1, __shfl_xor(m1, off));
    }
    if (lane == 0) { red[0][wv] = m0; red[1][wv] = m1; }
  }
  __syncthreads();
  {
    float m0 = red[0][0], m1 = red[1][0];
#pragma unroll
    for (int w2 = 1; w2 < 8; ++w2) { m0 = fmaxf(m0, red[0][w2]); m1 = fmaxf(m1, red[1][w2]); }
    __syncthreads();
    if (tid < 512) {
      e0 = __expf(x0 - m0); e1 = __expf(x1 - m1);
      float s0v = e0, s1v = e1;
#pragma unroll
      for (int off = 32; off; off >>= 1) {
        s0v += __shfl_xor(s0v, off);
        s1v += __shfl_xor(s1v, off);
      }
      if (lane == 0) { red[0][wv] = s0v; red[1][wv] = s1v; }
    }
  }
  __syncthreads();
  {
    float sum0 = 0.f, sum1 = 0.f;
#pragma unroll
    for (int w2 = 0; w2 < 8; ++w2) { sum0 += red[0][w2]; sum1 += red[1][w2]; }
    if (tid < 512) {
      const float a0 = e0 * __builtin_amdgcn_rcpf(sum0);
      const float a1 = e1 * __builtin_amdgcn_rcpf(sum1);
      align_out[(size_t)(t0 + 0) * BB * SS + b * SS + tid] = a0;
      align_out[(size_t)(t0 + 1) * BB * SS + b * SS + tid] = a1;
      sc[0][tid] = a0;
      sc[1][tid] = a1;
    }
  }
  __syncthreads();

  // ---- context: q = s-quarter (tid>>8), hp = h-pair (tid&255) ----
  {
    const int q = tid >> 8, hp = tid & 255;
    const unsigned* ep = (const unsigned*)encpb + (size_t)b * SS * 256;
    float c00 = 0.f, c01 = 0.f, c10 = 0.f, c11 = 0.f;
#pragma unroll 8
    for (int s2 = q * 128; s2 < q * 128 + 128; ++s2) {
      const unsigned u = ep[s2 * 256 + hp];
      const float elo = bflo(u);
      const float ehi = bfhi(u);
      const float av0 = sc[0][s2], av1 = sc[1][s2];
      c00 = fmaf(av0, elo, c00); c01 = fmaf(av0, ehi, c01);
      c10 = fmaf(av1, elo, c10); c11 = fmaf(av1, ehi, c11);
    }
    part[(0 * 4 + q) * 256 + hp] = make_float2(c00, c01);
    part[(1 * 4 + q) * 256 + hp] = make_float2(c10, c11);
  }
  __syncthreads();
  if (tid < 512) {
    const int t = tid >> 8, hp = tid & 255;
    float clo = 0.f, chi = 0.f;
#pragma unroll
    for (int q = 0; q < 4; ++q) {
      const float2 p = part[(t * 4 + q) * 256 + hp];
      clo += p.x; chi += p.y;
    }
    cs[t * 512 + hp * 2]     = clo;
    cs[t * 512 + hp * 2 + 1] = chi;
  }
  __syncthreads();

  // ---- fused output projection: attn_h[t,b,n] += c[t,:]·WoT_top[n,:] ----
  // e = lane&7 covers k = j*64 + e*8 (16B contiguous per lane, 8 lanes = 128B
  // per row); grp = lane>>3 -> 8 consecutive n-rows per wave; p-loop covers
  // n in [0,512) over 4 passes; both t per weight load.
  {
    const int e = lane & 7, grp = lane >> 3;
    const int nb = wv * 8 + grp;                        // [0,128)
    float acc[4][2] = {};
#pragma unroll
    for (int j = 0; j < 8; ++j) {
      const int k = j * 64 + e * 8;
      const float4 c00 = *(const float4*)(cs + k);
      const float4 c01 = *(const float4*)(cs + k + 4);
      const float4 c10 = *(const float4*)(cs + 512 + k);
      const float4 c11 = *(const float4*)(cs + 512 + k + 4);
#pragma unroll
      for (int p = 0; p < 4; ++p) {
        const int n = p * 128 + nb;
        const uint4 u = *(const uint4*)(WoT + (size_t)n * 1024 + k);
        const float w0 = bflo(u.x), w1 = bfhi(u.x);
        const float w2 = bflo(u.y), w3 = bfhi(u.y);
        const float w4 = bflo(u.z), w5 = bfhi(u.z);
        const float w6 = bflo(u.w), w7 = bfhi(u.w);
        float a0 = acc[p][0], a1 = acc[p][1];
        a0 = fmaf(c00.x, w0, a0); a1 = fmaf(c10.x, w0, a1);
        a0 = fmaf(c00.y, w1, a0); a1 = fmaf(c10.y, w1, a1);
        a0 = fmaf(c00.z, w2, a0); a1 = fmaf(c10.z, w2, a1);
        a0 = fmaf(c00.w, w3, a0); a1 = fmaf(c10.w, w3, a1);
        a0 = fmaf(c01.x, w4, a0); a1 = fmaf(c11.x, w4, a1);
        a0 = fmaf(c01.y, w5, a0); a1 = fmaf(c11.y, w5, a1);
        a0 = fmaf(c01.z, w6, a0); a1 = fmaf(c11.z, w6, a1);
        a0 = fmaf(c01.w, w7, a0); a1 = fmaf(c11.w, w7, a1);
        acc[p][0] = a0; acc[p][1] = a1;
      }
    }
#pragma unroll
    for (int p = 0; p < 4; ++p)
#pragma unroll
      for (int t = 0; t < 2; ++t) {
        float a = acc[p][t];
        a += __shfl_xor(a, 1);
        a += __shfl_xor(a, 2);
        a += __shfl_xor(a, 4);
        if (e == 0) {
          const int n = p * 128 + nb;
          attn_h[(size_t)((t0 + t) * BB + b) * 512 + n] += a;
        }
      }
  }
}

// ---------------------------------------------------------------------------
extern "C" void kernel_launch(void* const* d_in, const int* in_sizes, int n_in,
                              void* d_out, int out_size, void* d_ws, size_t ws_size,
                              hipStream_t stream) {
  const float* dec  = (const float*)d_in[0];
  const float* enc  = (const float*)d_in[1];
  const float* cov  = (const float*)d_in[2];
  const float* Wq   = (const float*)d_in[3];
  const float* bq   = (const float*)d_in[4];
  const float* Wc   = (const float*)d_in[5];
  const float* v    = (const float*)d_in[6];
  const float* Wo   = (const float*)d_in[7];
  const float* bo   = (const float*)d_in[8];
  const float* wcov = (const float*)d_in[9];

  float* out = (float*)d_out;
  float* attn_h    = out;                         // [T,B,H]
  float* align_out = out + (size_t)TT * BB * HH;  // [T,B,S]

  char* w = (char*)d_ws;
  const size_t MB = 1024 * 1024;
  unsigned short* encpb   = (unsigned short*)(w);                      // 4 MB
  unsigned short* WqT     = (unsigned short*)(w + 4 * MB);             // 0.5 MB
  unsigned short* WcT     = (unsigned short*)(w + 4 * MB + 512 * 1024);// 0.5 MB
  unsigned short* WoT     = (unsigned short*)(w + 5 * MB);             // 1 MB [n][1024]
  unsigned short* concatb = (unsigned short*)(w + 6 * MB);             // 1 MB [b*64+t][1024]
  float*          Ea1     = (float*)(w + 7 * MB);                      // 1 MB
  unsigned short* Ea2b    = (unsigned short*)(w + 8 * MB);             // 4 MB bf16

  k_prep<<<3328, 256, 0, stream>>>(enc, cov, wcov, dec, Wq, Wc, Wo,
                                   encpb, concatb, WqT, WcT, WoT);
  k_gemm12<<<640, 256, 0, stream>>>(concatb, encpb, WqT, WcT, WoT, bq, bo,
                                    Ea1, Ea2b, attn_h);
  k_attn<<<256, 1024, 0, stream>>>(Ea1, Ea2b, v, encpb, WoT, align_out, attn_h);
}

// Round 4
// 132.352 us; speedup vs baseline: 2.1361x; 2.1361x over previous
//
#include <hip/hip_runtime.h>
#include <cstddef>

static constexpr int TT = 64;    // decoder steps
static constexpr int BB = 8;     // batch
static constexpr int SS = 512;   // source length
static constexpr int HH = 512;   // hidden

typedef __attribute__((ext_vector_type(8))) short bf16x8;
typedef __attribute__((ext_vector_type(4))) float f32x4;

__device__ __forceinline__ float fast_tanh(float x) {
  float e = __expf(2.0f * x);
  return 1.0f - 2.0f * __builtin_amdgcn_rcpf(e + 1.0f);
}
__device__ __forceinline__ unsigned short f2bf(float f) {
  unsigned u = __float_as_uint(f);
  return (unsigned short)((u + 0x7FFFu + ((u >> 16) & 1u)) >> 16);   // RNE
}
__device__ __forceinline__ float bflo(unsigned u) { return __uint_as_float(u << 16); }
__device__ __forceinline__ float bfhi(unsigned u) { return __uint_as_float(u & 0xffff0000u); }

// ---------------------------------------------------------------------------
// k_prep — all preprocessing, vectorized (float4/ushort4):
//  [0,2048):     encpb = bf16(tanh(enc + cov*wcov)), 2 bs-rows/block
//  [2048,2304):  dec pack -> concatb right half, 2 m-rows/block
//  [2304,3328):  weight transposes Wq,Wc,Wo (32x32 tiles -> WT[n][k] bf16)
// ---------------------------------------------------------------------------
__global__ __launch_bounds__(256)
void k_prep(const float* __restrict__ enc, const float* __restrict__ cov,
            const float* __restrict__ wcov, const float* __restrict__ dec,
            const float* __restrict__ Wq, const float* __restrict__ Wc,
            const float* __restrict__ Wo,
            unsigned short* __restrict__ encpb, unsigned short* __restrict__ concatb,
            unsigned short* __restrict__ WqT, unsigned short* __restrict__ WcT,
            unsigned short* __restrict__ WoT) {
  __shared__ float tile[32][33];
  const int blk = blockIdx.x, tid = threadIdx.x;

  if (blk < 2048) {
    const int r = tid >> 7, c = (tid & 127) * 4;
    const int bs = blk * 2 + r;
    const int s = bs & 511, b = bs >> 9;
    const float4 ev = *(const float4*)(enc + (size_t)(s * BB + b) * HH + c);
    const float cv = cov[bs];
    const float4 wv = *(const float4*)(wcov + c);
    ushort4 o;
    o.x = f2bf(fast_tanh(ev.x + cv * wv.x));
    o.y = f2bf(fast_tanh(ev.y + cv * wv.y));
    o.z = f2bf(fast_tanh(ev.z + cv * wv.z));
    o.w = f2bf(fast_tanh(ev.w + cv * wv.w));
    *(ushort4*)(encpb + (size_t)bs * HH + c) = o;
  } else if (blk < 2304) {
    const int r = tid >> 7, c = (tid & 127) * 4;
    const int m = (blk - 2048) * 2 + r, t = m & 63, b = m >> 6;   // m = b*64+t
    const float4 dv = *(const float4*)(dec + (size_t)(t * BB + b) * HH + c);
    ushort4 o;
    o.x = f2bf(dv.x); o.y = f2bf(dv.y); o.z = f2bf(dv.z); o.w = f2bf(dv.w);
    *(ushort4*)(concatb + (size_t)m * 1024 + 512 + c) = o;
  } else {
    int l = blk - 2304;
    const float* W; unsigned short* WT; int KT;
    if (l < 256)      { W = Wq; WT = WqT; KT = 512; }
    else if (l < 512) { W = Wc; WT = WcT; KT = 512; l -= 256; }
    else              { W = Wo; WT = WoT; KT = 1024; l -= 512; }
    const int n0 = (l & 15) * 32, k0 = (l >> 4) * 32;
    const int r = tid >> 3, c4 = (tid & 7) * 4;
    const float4 w = *(const float4*)(W + (size_t)(k0 + r) * 512 + n0 + c4);
    tile[r][c4 + 0] = w.x; tile[r][c4 + 1] = w.y;
    tile[r][c4 + 2] = w.z; tile[r][c4 + 3] = w.w;
    __syncthreads();
    unsigned short* o = WT + (size_t)(n0 + r) * KT + k0 + c4;
#pragma unroll
    for (int i = 0; i < 4; ++i) o[i] = f2bf(tile[c4 + i][r]);
  }
}

// ---------------------------------------------------------------------------
// 64x64 bf16 MFMA tile over K range. 256 thr / 4 waves.
// C/D layout: col=lane&15, row=(lane>>4)*4+reg (verified earlier).
// ---------------------------------------------------------------------------
template<int LDA, int LDB>
__device__ __forceinline__ void gemm_tile(const unsigned short* __restrict__ A,
                                          const unsigned short* __restrict__ BT,
                                          int m0, int n0, int kbeg, int kend,
                                          unsigned short (*As)[72],
                                          unsigned short (*Bs)[72],
                                          f32x4 acc[4]) {
  const int tid = threadIdx.x, w = tid >> 6, lane = tid & 63;
  const int lr = tid >> 2, lk = (tid & 3) * 16;
  const int fm = w * 16 + (lane & 15), fk = (lane >> 4) * 8;
  for (int k0 = kbeg; k0 < kend; k0 += 64) {
    const uint4* ga = (const uint4*)(A + (size_t)(m0 + lr) * LDA + k0 + lk);
    const uint4* gb = (const uint4*)(BT + (size_t)(n0 + lr) * LDB + k0 + lk);
    uint4 a0 = ga[0], a1 = ga[1], b0 = gb[0], b1 = gb[1];
    *(uint4*)&As[lr][lk] = a0;  *(uint4*)&As[lr][lk + 8] = a1;
    *(uint4*)&Bs[lr][lk] = b0;  *(uint4*)&Bs[lr][lk + 8] = b1;
    __syncthreads();
#pragma unroll
    for (int ks = 0; ks < 2; ++ks) {
      bf16x8 af = *(const bf16x8*)&As[fm][ks * 32 + fk];
#pragma unroll
      for (int j = 0; j < 4; ++j) {
        bf16x8 bf = *(const bf16x8*)&Bs[j * 16 + (lane & 15)][ks * 32 + fk];
        acc[j] = __builtin_amdgcn_mfma_f32_16x16x32_bf16(af, bf, acc[j], 0, 0, 0);
      }
    }
    __syncthreads();
  }
}

// ---------------------------------------------------------------------------
// k_gemm12 — three GEMM jobs in ONE launch (640 blocks):
//  g <  64: Ea1 (fp32) = exp(2*clamp(dec@Wq + bq, +-10.5))
//  g < 576: Ea2b (BF16) = exp(2*clamp(encp@Wc, +-10.5))   <- halves L2 stream
//  g < 640: attn_h base = dec@Wo_bot + bo (scattered [T,B,H]); k_out adds c@Wo_top
// clamp +-10.5: pair-product (Ea1*Ea2+1)^2 <= 2.9e36 finite; tanh(10.5)=1-1.5e-9.
// ---------------------------------------------------------------------------
__global__ __launch_bounds__(256)
void k_gemm12(const unsigned short* __restrict__ concatb,
              const unsigned short* __restrict__ encpb,
              const unsigned short* __restrict__ WqT,
              const unsigned short* __restrict__ WcT,
              const unsigned short* __restrict__ WoT,
              const float* __restrict__ bq, const float* __restrict__ bo,
              float* __restrict__ Ea1, unsigned short* __restrict__ Ea2b,
              float* __restrict__ attn_h) {
  __shared__ unsigned short As[64][72];
  __shared__ unsigned short Bs[64][72];
  const int g = blockIdx.x, tid = threadIdx.x;
  const int w = tid >> 6, lane = tid & 63;
  const int col = lane & 15, rq = lane >> 4;

  if (g < 64) {                        // a1
    const int m0 = (g >> 3) * 64, n0 = (g & 7) * 64;
    f32x4 acc[4] = {};
    gemm_tile<1024, 512>(concatb + 512, WqT, m0, n0, 0, 512, As, Bs, acc);
#pragma unroll
    for (int j = 0; j < 4; ++j) {
      const int n = n0 + j * 16 + col;
      const float bv = bq[n];
#pragma unroll
      for (int r = 0; r < 4; ++r) {
        const int m = m0 + w * 16 + rq * 4 + r;
        float val = fminf(fmaxf(acc[j][r] + bv, -10.5f), 10.5f);
        Ea1[(size_t)m * 512 + n] = __expf(2.0f * val);
      }
    }
  } else if (g < 576) {                // a2 -> bf16
    const int u = g - 64;
    const int m0 = (u >> 3) * 64, n0 = (u & 7) * 64;
    f32x4 acc[4] = {};
    gemm_tile<512, 512>(encpb, WcT, m0, n0, 0, 512, As, Bs, acc);
#pragma unroll
    for (int j = 0; j < 4; ++j) {
      const int n = n0 + j * 16 + col;
#pragma unroll
      for (int r = 0; r < 4; ++r) {
        const int m = m0 + w * 16 + rq * 4 + r;
        float val = fminf(fmaxf(acc[j][r], -10.5f), 10.5f);
        Ea2b[(size_t)m * 512 + n] = f2bf(__expf(2.0f * val));
      }
    }
  } else {                             // attn_h base = dec@Wo_bot + bo
    const int u = g - 576;
    const int m0 = (u >> 3) * 64, n0 = (u & 7) * 64;
    f32x4 acc[4] = {};
    gemm_tile<1024, 1024>(concatb, WoT, m0, n0, 512, 1024, As, Bs, acc);
#pragma unroll
    for (int j = 0; j < 4; ++j) {
      const int n = n0 + j * 16 + col;
      const float bv = bo[n];
#pragma unroll
      for (int r = 0; r < 4; ++r) {
        const int m = m0 + w * 16 + rq * 4 + r;
        const int bi = m >> 6, t = m & 63;
        attn_h[(size_t)(t * BB + bi) * 512 + n] = acc[j][r] + bv;
      }
    }
  }
}

// ---------------------------------------------------------------------------
// k_attn — scores + softmax + context; 512 blocks (b, single t), 1024 thr.
// One-t blocks double occupancy vs the r0 t-pair version: 2 blocks/CU,
// 32 waves/CU (max) to hide the L2/LDS latency that capped the t-pair
// version at ~34us (VALUBusy 37%, Occupancy 35%). Total VALU unchanged;
// Ea2b/encpb L2 volume doubles (~256MB aggregate = ~7us at 34.5TB/s, hidden).
// Scores (pair-rcp, bf16 Ea2): sc = -(sum_h 2 v_h/(Ea1*Ea2+1)).
// ---------------------------------------------------------------------------
__global__ __launch_bounds__(1024)
void k_attn(const float* __restrict__ Ea1, const unsigned short* __restrict__ Ea2b,
            const float* __restrict__ v, const unsigned short* __restrict__ encpb,
            float* __restrict__ align_out, unsigned short* __restrict__ concatb) {
  __shared__ __align__(16) char smem[10304];
  float* sc    = (float*)smem;              // [512] scores -> align
  float* ea1s  = (float*)(smem + 2048);     // [512] (scores phase)
  float* v2s   = (float*)(smem + 4096);     // [512] (scores phase)
  float2* part = (float2*)(smem + 2048);    // [4][256] (ctx phase, reuses ea1s/v2s)
  float* red   = (float*)(smem + 10240);    // [8]

  const int g = blockIdx.x, tid = threadIdx.x;
  const int b = g & 7, t = g >> 3;                     // XCD-affine b
  const int wv = tid >> 6, lane = tid & 63;
  const int hq = lane & 3, sl = lane >> 2;

  if (tid < 512) {
    ea1s[tid] = Ea1[(size_t)(b * TT + t) * HH + tid];
  } else {
    v2s[tid - 512] = 2.0f * v[tid - 512];
  }
  __syncthreads();

  // ---- scores: 16 waves x 32 s, one pass; 32-h chunks (8 bf16/lane-load) ----
  const int s0 = wv * 32 + sl;                         // and s0+16
  {
    const unsigned short* e2r0 = Ea2b + (size_t)(b * SS + s0) * HH;
    const unsigned short* e2r1 = e2r0 + (size_t)16 * HH;
    float acc0 = 0.f, acc1 = 0.f;
#define PAIR(E1a, E2a, Va, E1b, E2b, Vb, A)                                  \
    {                                                                        \
      const float x1 = fmaf(E1a, E2a, 1.0f), x2 = fmaf(E1b, E2b, 1.0f);      \
      const float rr = __builtin_amdgcn_rcpf(x1 * x2);                       \
      const float nn = fmaf(Va, x2, Vb * x1);                                \
      A = fmaf(nn, rr, A);                                                   \
    }
#pragma unroll 4
    for (int it = 0; it < 16; ++it) {
      const int h = it * 32 + hq * 8;
      const uint4 u0 = *(const uint4*)(e2r0 + h);
      const uint4 u1 = *(const uint4*)(e2r1 + h);
      const float4 va = *(const float4*)&v2s[h];
      const float4 vb = *(const float4*)&v2s[h + 4];
      const float4 e1a = *(const float4*)&ea1s[h];
      const float4 e1b = *(const float4*)&ea1s[h + 4];
      PAIR(e1a.x, bflo(u0.x), va.x, e1a.y, bfhi(u0.x), va.y, acc0);
      PAIR(e1a.z, bflo(u0.y), va.z, e1a.w, bfhi(u0.y), va.w, acc0);
      PAIR(e1b.x, bflo(u0.z), vb.x, e1b.y, bfhi(u0.z), vb.y, acc0);
      PAIR(e1b.z, bflo(u0.w), vb.z, e1b.w, bfhi(u0.w), vb.w, acc0);
      PAIR(e1a.x, bflo(u1.x), va.x, e1a.y, bfhi(u1.x), va.y, acc1);
      PAIR(e1a.z, bflo(u1.y), va.z, e1a.w, bfhi(u1.y), va.w, acc1);
      PAIR(e1b.x, bflo(u1.z), vb.x, e1b.y, bfhi(u1.z), vb.y, acc1);
      PAIR(e1b.z, bflo(u1.w), vb.z, e1b.w, bfhi(u1.w), vb.w, acc1);
    }
#undef PAIR
    acc0 += __shfl_xor(acc0, 1); acc0 += __shfl_xor(acc0, 2);
    acc1 += __shfl_xor(acc1, 1); acc1 += __shfl_xor(acc1, 2);
    if (hq == 0) {
      sc[s0] = -acc0; sc[s0 + 16] = -acc1;
    }
  }
  __syncthreads();

  // ---- softmax over s (threads < 512 own s=tid; all threads hit barriers) --
  float x0 = 0.f, e0 = 0.f;
  if (tid < 512) {
    x0 = sc[tid];
    float m0 = x0;
#pragma unroll
    for (int off = 32; off; off >>= 1) m0 = fmaxf(m0, __shfl_xor(m0, off));
    if (lane == 0) red[wv] = m0;
  }
  __syncthreads();
  {
    float m0 = red[0];
#pragma unroll
    for (int w2 = 1; w2 < 8; ++w2) m0 = fmaxf(m0, red[w2]);
    __syncthreads();
    if (tid < 512) {
      e0 = __expf(x0 - m0);
      float s0v = e0;
#pragma unroll
      for (int off = 32; off; off >>= 1) s0v += __shfl_xor(s0v, off);
      if (lane == 0) red[wv] = s0v;
    }
  }
  __syncthreads();
  {
    float sum0 = 0.f;
#pragma unroll
    for (int w2 = 0; w2 < 8; ++w2) sum0 += red[w2];
    if (tid < 512) {
      const float a0 = e0 * __builtin_amdgcn_rcpf(sum0);
      align_out[(size_t)t * BB * SS + b * SS + tid] = a0;
      sc[tid] = a0;
    }
  }
  __syncthreads();

  // ---- context: q = s-quarter (tid>>8), hp = h-pair (tid&255) ----
  {
    const int q = tid >> 8, hp = tid & 255;
    const unsigned* ep = (const unsigned*)encpb + (size_t)b * SS * 256;
    float c00 = 0.f, c01 = 0.f;
#pragma unroll 8
    for (int s2 = q * 128; s2 < q * 128 + 128; ++s2) {
      const unsigned u = ep[s2 * 256 + hp];
      const float av0 = sc[s2];
      c00 = fmaf(av0, bflo(u), c00);
      c01 = fmaf(av0, bfhi(u), c01);
    }
    part[q * 256 + hp] = make_float2(c00, c01);
  }
  __syncthreads();
  if (tid < 256) {
    const int hp = tid;
    float clo = 0.f, chi = 0.f;
#pragma unroll
    for (int q = 0; q < 4; ++q) {
      const float2 p = part[q * 256 + hp];
      clo += p.x; chi += p.y;
    }
    ((unsigned*)concatb)[(size_t)(b * TT + t) * 512 + hp] =
        (unsigned)f2bf(clo) | ((unsigned)f2bf(chi) << 16);
  }
}

// ---------------------------------------------------------------------------
// k_out — attn_h += c@Wo_top (K=512), split-K x4 via HW fp32 atomics on the
// base (dec@Wo_bot + bo) written by k_gemm12. 256 blocks.
// ---------------------------------------------------------------------------
__global__ __launch_bounds__(256)
void k_out(const unsigned short* __restrict__ A,
           const unsigned short* __restrict__ BT,
           float* __restrict__ C) {
  __shared__ unsigned short As[64][72];
  __shared__ unsigned short Bs[64][72];
  const int tid = threadIdx.x;
  const int w = tid >> 6, lane = tid & 63;
  const int tau = blockIdx.x >> 2, kc = blockIdx.x & 3;
  const int n0 = (tau & 7) * 64, m0 = (tau >> 3) * 64;

  f32x4 acc[4] = {};
  gemm_tile<1024, 1024>(A, BT, m0, n0, kc * 128, kc * 128 + 128, As, Bs, acc);

  const int col = lane & 15, rq = lane >> 4;
#pragma unroll
  for (int j = 0; j < 4; ++j) {
    const int n = n0 + j * 16 + col;
#pragma unroll
    for (int r = 0; r < 4; ++r) {
      const int m = m0 + w * 16 + rq * 4 + r;
      const int bi = m >> 6, t = m & 63;
      unsafeAtomicAdd(&C[(size_t)(t * BB + bi) * 512 + n], acc[j][r]);
    }
  }
}

// ---------------------------------------------------------------------------
extern "C" void kernel_launch(void* const* d_in, const int* in_sizes, int n_in,
                              void* d_out, int out_size, void* d_ws, size_t ws_size,
                              hipStream_t stream) {
  const float* dec  = (const float*)d_in[0];
  const float* enc  = (const float*)d_in[1];
  const float* cov  = (const float*)d_in[2];
  const float* Wq   = (const float*)d_in[3];
  const float* bq   = (const float*)d_in[4];
  const float* Wc   = (const float*)d_in[5];
  const float* v    = (const float*)d_in[6];
  const float* Wo   = (const float*)d_in[7];
  const float* bo   = (const float*)d_in[8];
  const float* wcov = (const float*)d_in[9];

  float* out = (float*)d_out;
  float* attn_h    = out;                         // [T,B,H]
  float* align_out = out + (size_t)TT * BB * HH;  // [T,B,S]

  char* w = (char*)d_ws;
  const size_t MB = 1024 * 1024;
  unsigned short* encpb   = (unsigned short*)(w);                      // 4 MB
  unsigned short* WqT     = (unsigned short*)(w + 4 * MB);             // 0.5 MB
  unsigned short* WcT     = (unsigned short*)(w + 4 * MB + 512 * 1024);// 0.5 MB
  unsigned short* WoT     = (unsigned short*)(w + 5 * MB);             // 1 MB [n][1024]
  unsigned short* concatb = (unsigned short*)(w + 6 * MB);             // 1 MB [b*64+t][1024]
  float*          Ea1     = (float*)(w + 7 * MB);                      // 1 MB
  unsigned short* Ea2b    = (unsigned short*)(w + 8 * MB);             // 4 MB bf16

  k_prep<<<3328, 256, 0, stream>>>(enc, cov, wcov, dec, Wq, Wc, Wo,
                                   encpb, concatb, WqT, WcT, WoT);
  k_gemm12<<<640, 256, 0, stream>>>(concatb, encpb, WqT, WcT, WoT, bq, bo,
                                    Ea1, Ea2b, attn_h);
  k_attn<<<512, 1024, 0, stream>>>(Ea1, Ea2b, v, encpb, align_out, concatb);
  k_out<<<256, 256, 0, stream>>>(concatb, WoT, attn_h);
}

// Round 5
// 126.287 us; speedup vs baseline: 2.2386x; 1.0480x over previous
//
#include <hip/hip_runtime.h>
#include <cstddef>

static constexpr int TT = 64;    // decoder steps
static constexpr int BB = 8;     // batch
static constexpr int SS = 512;   // source length
static constexpr int HH = 512;   // hidden

typedef __attribute__((ext_vector_type(8))) short bf16x8;
typedef __attribute__((ext_vector_type(4))) float f32x4;

__device__ __forceinline__ float fast_tanh(float x) {
  float e = __expf(2.0f * x);
  return 1.0f - 2.0f * __builtin_amdgcn_rcpf(e + 1.0f);
}
__device__ __forceinline__ unsigned short f2bf(float f) {
  unsigned u = __float_as_uint(f);
  return (unsigned short)((u + 0x7FFFu + ((u >> 16) & 1u)) >> 16);   // RNE
}
__device__ __forceinline__ float bflo(unsigned u) { return __uint_as_float(u << 16); }
__device__ __forceinline__ float bfhi(unsigned u) { return __uint_as_float(u & 0xffff0000u); }

// ---------------------------------------------------------------------------
// k_prep — all preprocessing, vectorized (float4/ushort4):
//  [0,2048):     encpb = bf16(tanh(enc + cov*wcov)), 2 bs-rows/block
//  [2048,2304):  dec pack -> concatb right half, 2 m-rows/block
//  [2304,3328):  weight transposes Wq,Wc,Wo (32x32 tiles -> WT[n][k] bf16)
// ---------------------------------------------------------------------------
__global__ __launch_bounds__(256)
void k_prep(const float* __restrict__ enc, const float* __restrict__ cov,
            const float* __restrict__ wcov, const float* __restrict__ dec,
            const float* __restrict__ Wq, const float* __restrict__ Wc,
            const float* __restrict__ Wo,
            unsigned short* __restrict__ encpb, unsigned short* __restrict__ concatb,
            unsigned short* __restrict__ WqT, unsigned short* __restrict__ WcT,
            unsigned short* __restrict__ WoT) {
  __shared__ float tile[32][33];
  const int blk = blockIdx.x, tid = threadIdx.x;

  if (blk < 2048) {
    const int r = tid >> 7, c = (tid & 127) * 4;
    const int bs = blk * 2 + r;
    const int s = bs & 511, b = bs >> 9;
    const float4 ev = *(const float4*)(enc + (size_t)(s * BB + b) * HH + c);
    const float cv = cov[bs];
    const float4 wv = *(const float4*)(wcov + c);
    ushort4 o;
    o.x = f2bf(fast_tanh(ev.x + cv * wv.x));
    o.y = f2bf(fast_tanh(ev.y + cv * wv.y));
    o.z = f2bf(fast_tanh(ev.z + cv * wv.z));
    o.w = f2bf(fast_tanh(ev.w + cv * wv.w));
    *(ushort4*)(encpb + (size_t)bs * HH + c) = o;
  } else if (blk < 2304) {
    const int r = tid >> 7, c = (tid & 127) * 4;
    const int m = (blk - 2048) * 2 + r, t = m & 63, b = m >> 6;   // m = b*64+t
    const float4 dv = *(const float4*)(dec + (size_t)(t * BB + b) * HH + c);
    ushort4 o;
    o.x = f2bf(dv.x); o.y = f2bf(dv.y); o.z = f2bf(dv.z); o.w = f2bf(dv.w);
    *(ushort4*)(concatb + (size_t)m * 1024 + 512 + c) = o;
  } else {
    int l = blk - 2304;
    const float* W; unsigned short* WT; int KT;
    if (l < 256)      { W = Wq; WT = WqT; KT = 512; }
    else if (l < 512) { W = Wc; WT = WcT; KT = 512; l -= 256; }
    else              { W = Wo; WT = WoT; KT = 1024; l -= 512; }
    const int n0 = (l & 15) * 32, k0 = (l >> 4) * 32;
    const int r = tid >> 3, c4 = (tid & 7) * 4;
    const float4 w = *(const float4*)(W + (size_t)(k0 + r) * 512 + n0 + c4);
    tile[r][c4 + 0] = w.x; tile[r][c4 + 1] = w.y;
    tile[r][c4 + 2] = w.z; tile[r][c4 + 3] = w.w;
    __syncthreads();
    unsigned short* o = WT + (size_t)(n0 + r) * KT + k0 + c4;
#pragma unroll
    for (int i = 0; i < 4; ++i) o[i] = f2bf(tile[c4 + i][r]);
  }
}

// ---------------------------------------------------------------------------
// 64x64 bf16 MFMA tile over K range. 256 thr / 4 waves.
// C/D layout: col=lane&15, row=(lane>>4)*4+reg (verified earlier).
// ---------------------------------------------------------------------------
template<int LDA, int LDB>
__device__ __forceinline__ void gemm_tile(const unsigned short* __restrict__ A,
                                          const unsigned short* __restrict__ BT,
                                          int m0, int n0, int kbeg, int kend,
                                          unsigned short (*As)[72],
                                          unsigned short (*Bs)[72],
                                          f32x4 acc[4]) {
  const int tid = threadIdx.x, w = tid >> 6, lane = tid & 63;
  const int lr = tid >> 2, lk = (tid & 3) * 16;
  const int fm = w * 16 + (lane & 15), fk = (lane >> 4) * 8;
  for (int k0 = kbeg; k0 < kend; k0 += 64) {
    const uint4* ga = (const uint4*)(A + (size_t)(m0 + lr) * LDA + k0 + lk);
    const uint4* gb = (const uint4*)(BT + (size_t)(n0 + lr) * LDB + k0 + lk);
    uint4 a0 = ga[0], a1 = ga[1], b0 = gb[0], b1 = gb[1];
    *(uint4*)&As[lr][lk] = a0;  *(uint4*)&As[lr][lk + 8] = a1;
    *(uint4*)&Bs[lr][lk] = b0;  *(uint4*)&Bs[lr][lk + 8] = b1;
    __syncthreads();
#pragma unroll
    for (int ks = 0; ks < 2; ++ks) {
      bf16x8 af = *(const bf16x8*)&As[fm][ks * 32 + fk];
#pragma unroll
      for (int j = 0; j < 4; ++j) {
        bf16x8 bf = *(const bf16x8*)&Bs[j * 16 + (lane & 15)][ks * 32 + fk];
        acc[j] = __builtin_amdgcn_mfma_f32_16x16x32_bf16(af, bf, acc[j], 0, 0, 0);
      }
    }
    __syncthreads();
  }
}

// ---------------------------------------------------------------------------
// k_gemm12 — three GEMM jobs in ONE launch (640 blocks):
//  g <  64: Ea1 (fp32) = exp(2*clamp(dec@Wq + bq, +-10.5))
//  g < 576: Ea2b (BF16) = exp(2*clamp(encp@Wc, +-10.5))   <- halves L2 stream
//  g < 640: attn_h base = dec@Wo_bot + bo (scattered [T,B,H]); k_out adds c@Wo_top
// clamp +-10.5: pair-product (Ea1*Ea2+1)^2 <= 2.9e36 finite; tanh(10.5)=1-1.5e-9.
// ---------------------------------------------------------------------------
__global__ __launch_bounds__(256)
void k_gemm12(const unsigned short* __restrict__ concatb,
              const unsigned short* __restrict__ encpb,
              const unsigned short* __restrict__ WqT,
              const unsigned short* __restrict__ WcT,
              const unsigned short* __restrict__ WoT,
              const float* __restrict__ bq, const float* __restrict__ bo,
              float* __restrict__ Ea1, unsigned short* __restrict__ Ea2b,
              float* __restrict__ attn_h) {
  __shared__ unsigned short As[64][72];
  __shared__ unsigned short Bs[64][72];
  const int g = blockIdx.x, tid = threadIdx.x;
  const int w = tid >> 6, lane = tid & 63;
  const int col = lane & 15, rq = lane >> 4;

  if (g < 64) {                        // a1
    const int m0 = (g >> 3) * 64, n0 = (g & 7) * 64;
    f32x4 acc[4] = {};
    gemm_tile<1024, 512>(concatb + 512, WqT, m0, n0, 0, 512, As, Bs, acc);
#pragma unroll
    for (int j = 0; j < 4; ++j) {
      const int n = n0 + j * 16 + col;
      const float bv = bq[n];
#pragma unroll
      for (int r = 0; r < 4; ++r) {
        const int m = m0 + w * 16 + rq * 4 + r;
        float val = fminf(fmaxf(acc[j][r] + bv, -10.5f), 10.5f);
        Ea1[(size_t)m * 512 + n] = __expf(2.0f * val);
      }
    }
  } else if (g < 576) {                // a2 -> bf16
    const int u = g - 64;
    const int m0 = (u >> 3) * 64, n0 = (u & 7) * 64;
    f32x4 acc[4] = {};
    gemm_tile<512, 512>(encpb, WcT, m0, n0, 0, 512, As, Bs, acc);
#pragma unroll
    for (int j = 0; j < 4; ++j) {
      const int n = n0 + j * 16 + col;
#pragma unroll
      for (int r = 0; r < 4; ++r) {
        const int m = m0 + w * 16 + rq * 4 + r;
        float val = fminf(fmaxf(acc[j][r], -10.5f), 10.5f);
        Ea2b[(size_t)m * 512 + n] = f2bf(__expf(2.0f * val));
      }
    }
  } else {                             // attn_h base = dec@Wo_bot + bo
    const int u = g - 576;
    const int m0 = (u >> 3) * 64, n0 = (u & 7) * 64;
    f32x4 acc[4] = {};
    gemm_tile<1024, 1024>(concatb, WoT, m0, n0, 512, 1024, As, Bs, acc);
#pragma unroll
    for (int j = 0; j < 4; ++j) {
      const int n = n0 + j * 16 + col;
      const float bv = bo[n];
#pragma unroll
      for (int r = 0; r < 4; ++r) {
        const int m = m0 + w * 16 + rq * 4 + r;
        const int bi = m >> 6, t = m & 63;
        attn_h[(size_t)(t * BB + bi) * 512 + n] = acc[j][r] + bv;
      }
    }
  }
}

// ---------------------------------------------------------------------------
// k_attn — scores + softmax + context; 256 blocks (b, t-pair), 1024 thr.
// t-pair = verified best reuse point (r4 t-single: +8us from doubled L2 reads).
// This version adds ILP, not waves (grid is 1 block/CU, fixed):
//  - scores loop FULLY unrolled -> all 32 Ea2b uint4 loads schedulable early
//    (r0 had VGPR=40: compiler built almost no load pipeline; budget is 128)
//  - context loop uses uint2 (h-quad/thread): 64x8B loads instead of 128x4B
// Scores (pair-rcp, bf16 Ea2): sc = -(sum_h 2 v_h/(Ea1*Ea2+1)).
// ---------------------------------------------------------------------------
__global__ __launch_bounds__(1024)
void k_attn(const float* __restrict__ Ea1, const unsigned short* __restrict__ Ea2b,
            const float* __restrict__ v, const unsigned short* __restrict__ encpb,
            float* __restrict__ align_out, unsigned short* __restrict__ concatb) {
  __shared__ __align__(16) char smem[36928];
  float (*sc)[512]   = (float(*)[512])smem;            // [2][512] scores->align
  float (*ea1s)[512] = (float(*)[512])(smem + 4096);   // [2][512] (scores phase)
  float* v2s         = (float*)(smem + 12288);         // [512]    (scores phase)
  float (*red)[8]    = (float(*)[8])(smem + 14336);    // [2][8]   (softmax phase)
  float4* part4      = (float4*)(smem + 4096);         // [2][8][128] (ctx phase)

  const int g = blockIdx.x, tid = threadIdx.x;
  const int b = g & 7, t0 = (g >> 3) * 2;              // XCD-affine b
  const int wv = tid >> 6, lane = tid & 63;
  const int hq = lane & 3, sl = lane >> 2;

  if (tid < 512) {
    ea1s[0][tid] = Ea1[(size_t)(b * TT + t0) * HH + tid];
    ea1s[1][tid] = Ea1[(size_t)(b * TT + t0 + 1) * HH + tid];
  } else {
    v2s[tid - 512] = 2.0f * v[tid - 512];
  }
  __syncthreads();

  // ---- scores: 16 waves x 32 s, one pass; fully unrolled h-loop ----
  const int s0 = wv * 32 + sl;                         // and s0+16
  {
    const unsigned short* e2r0 = Ea2b + (size_t)(b * SS + s0) * HH;
    const unsigned short* e2r1 = e2r0 + (size_t)16 * HH;
    float acc[2][2] = {};
#define PAIR(E1a, E2a, Va, E1b, E2b, Vb, A)                                  \
    {                                                                        \
      const float x1 = fmaf(E1a, E2a, 1.0f), x2 = fmaf(E1b, E2b, 1.0f);      \
      const float rr = __builtin_amdgcn_rcpf(x1 * x2);                       \
      const float nn = fmaf(Va, x2, Vb * x1);                                \
      A = fmaf(nn, rr, A);                                                   \
    }
#pragma unroll
    for (int it = 0; it < 16; ++it) {
      const int h = it * 32 + hq * 8;
      const uint4 u0 = *(const uint4*)(e2r0 + h);
      const uint4 u1 = *(const uint4*)(e2r1 + h);
      const float4 va = *(const float4*)&v2s[h];
      const float4 vb = *(const float4*)&v2s[h + 4];
      float4 e1a[2], e1b[2];
      e1a[0] = *(const float4*)&ea1s[0][h]; e1b[0] = *(const float4*)&ea1s[0][h + 4];
      e1a[1] = *(const float4*)&ea1s[1][h]; e1b[1] = *(const float4*)&ea1s[1][h + 4];
#pragma unroll
      for (int i = 0; i < 2; ++i) {
        PAIR(e1a[i].x, bflo(u0.x), va.x, e1a[i].y, bfhi(u0.x), va.y, acc[i][0]);
        PAIR(e1a[i].z, bflo(u0.y), va.z, e1a[i].w, bfhi(u0.y), va.w, acc[i][0]);
        PAIR(e1b[i].x, bflo(u0.z), vb.x, e1b[i].y, bfhi(u0.z), vb.y, acc[i][0]);
        PAIR(e1b[i].z, bflo(u0.w), vb.z, e1b[i].w, bfhi(u0.w), vb.w, acc[i][0]);
        PAIR(e1a[i].x, bflo(u1.x), va.x, e1a[i].y, bfhi(u1.x), va.y, acc[i][1]);
        PAIR(e1a[i].z, bflo(u1.y), va.z, e1a[i].w, bfhi(u1.y), va.w, acc[i][1]);
        PAIR(e1b[i].x, bflo(u1.z), vb.x, e1b[i].y, bfhi(u1.z), vb.y, acc[i][1]);
        PAIR(e1b[i].z, bflo(u1.w), vb.z, e1b[i].w, bfhi(u1.w), vb.w, acc[i][1]);
      }
    }
#undef PAIR
#pragma unroll
    for (int i = 0; i < 2; ++i)
#pragma unroll
      for (int j = 0; j < 2; ++j) {
        acc[i][j] += __shfl_xor(acc[i][j], 1);
        acc[i][j] += __shfl_xor(acc[i][j], 2);
      }
    if (hq == 0) {
      sc[0][s0] = -acc[0][0]; sc[0][s0 + 16] = -acc[0][1];
      sc[1][s0] = -acc[1][0]; sc[1][s0 + 16] = -acc[1][1];
    }
  }
  __syncthreads();

  // ---- softmax over s (threads < 512 own s=tid; all threads hit barriers) --
  float x0 = 0.f, x1 = 0.f, e0 = 0.f, e1 = 0.f;
  if (tid < 512) {
    x0 = sc[0][tid]; x1 = sc[1][tid];
    float m0 = x0, m1 = x1;
#pragma unroll
    for (int off = 32; off; off >>= 1) {
      m0 = fmaxf(m0, __shfl_xor(m0, off));
      m1 = fmaxf(m1, __shfl_xor(m1, off));
    }
    if (lane == 0) { red[0][wv] = m0; red[1][wv] = m1; }
  }
  __syncthreads();
  {
    float m0 = red[0][0], m1 = red[1][0];
#pragma unroll
    for (int w2 = 1; w2 < 8; ++w2) { m0 = fmaxf(m0, red[0][w2]); m1 = fmaxf(m1, red[1][w2]); }
    __syncthreads();
    if (tid < 512) {
      e0 = __expf(x0 - m0); e1 = __expf(x1 - m1);
      float s0v = e0, s1v = e1;
#pragma unroll
      for (int off = 32; off; off >>= 1) {
        s0v += __shfl_xor(s0v, off);
        s1v += __shfl_xor(s1v, off);
      }
      if (lane == 0) { red[0][wv] = s0v; red[1][wv] = s1v; }
    }
  }
  __syncthreads();
  {
    float sum0 = 0.f, sum1 = 0.f;
#pragma unroll
    for (int w2 = 0; w2 < 8; ++w2) { sum0 += red[0][w2]; sum1 += red[1][w2]; }
    if (tid < 512) {
      const float a0 = e0 * __builtin_amdgcn_rcpf(sum0);
      const float a1 = e1 * __builtin_amdgcn_rcpf(sum1);
      align_out[(size_t)(t0 + 0) * BB * SS + b * SS + tid] = a0;
      align_out[(size_t)(t0 + 1) * BB * SS + b * SS + tid] = a1;
      sc[0][tid] = a0;
      sc[1][tid] = a1;
    }
  }
  __syncthreads();

  // ---- context: q = s-octant (tid>>7), hp2 = h-quad (tid&127), uint2 loads --
  {
    const int q = tid >> 7, hp2 = tid & 127;
    const uint2* ep2 = (const uint2*)encpb + (size_t)b * SS * 128;
    float4 cA = {0.f, 0.f, 0.f, 0.f}, cB = {0.f, 0.f, 0.f, 0.f};
    const int sbeg = q * 64;
#pragma unroll 8
    for (int s2 = sbeg; s2 < sbeg + 64; ++s2) {
      const uint2 u = ep2[(size_t)s2 * 128 + hp2];
      const float av0 = sc[0][s2], av1 = sc[1][s2];
      const float w0 = bflo(u.x), w1 = bfhi(u.x);
      const float w2 = bflo(u.y), w3 = bfhi(u.y);
      cA.x = fmaf(av0, w0, cA.x); cA.y = fmaf(av0, w1, cA.y);
      cA.z = fmaf(av0, w2, cA.z); cA.w = fmaf(av0, w3, cA.w);
      cB.x = fmaf(av1, w0, cB.x); cB.y = fmaf(av1, w1, cB.y);
      cB.z = fmaf(av1, w2, cB.z); cB.w = fmaf(av1, w3, cB.w);
    }
    part4[(0 * 8 + q) * 128 + hp2] = cA;
    part4[(1 * 8 + q) * 128 + hp2] = cB;
  }
  __syncthreads();
  if (tid < 256) {
    const int t = tid >> 7, hp2 = tid & 127;
    float4 c = {0.f, 0.f, 0.f, 0.f};
#pragma unroll
    for (int q = 0; q < 8; ++q) {
      const float4 p = part4[(t * 8 + q) * 128 + hp2];
      c.x += p.x; c.y += p.y; c.z += p.z; c.w += p.w;
    }
    uint2 o;
    o.x = (unsigned)f2bf(c.x) | ((unsigned)f2bf(c.y) << 16);
    o.y = (unsigned)f2bf(c.z) | ((unsigned)f2bf(c.w) << 16);
    ((uint2*)concatb)[(size_t)(b * TT + t0 + t) * 256 + hp2] = o;
  }
}

// ---------------------------------------------------------------------------
// k_out — attn_h += c@Wo_top (K=512), split-K x4 via HW fp32 atomics on the
// base (dec@Wo_bot + bo) written by k_gemm12. 256 blocks.
// ---------------------------------------------------------------------------
__global__ __launch_bounds__(256)
void k_out(const unsigned short* __restrict__ A,
           const unsigned short* __restrict__ BT,
           float* __restrict__ C) {
  __shared__ unsigned short As[64][72];
  __shared__ unsigned short Bs[64][72];
  const int tid = threadIdx.x;
  const int w = tid >> 6, lane = tid & 63;
  const int tau = blockIdx.x >> 2, kc = blockIdx.x & 3;
  const int n0 = (tau & 7) * 64, m0 = (tau >> 3) * 64;

  f32x4 acc[4] = {};
  gemm_tile<1024, 1024>(A, BT, m0, n0, kc * 128, kc * 128 + 128, As, Bs, acc);

  const int col = lane & 15, rq = lane >> 4;
#pragma unroll
  for (int j = 0; j < 4; ++j) {
    const int n = n0 + j * 16 + col;
#pragma unroll
    for (int r = 0; r < 4; ++r) {
      const int m = m0 + w * 16 + rq * 4 + r;
      const int bi = m >> 6, t = m & 63;
      unsafeAtomicAdd(&C[(size_t)(t * BB + bi) * 512 + n], acc[j][r]);
    }
  }
}

// ---------------------------------------------------------------------------
extern "C" void kernel_launch(void* const* d_in, const int* in_sizes, int n_in,
                              void* d_out, int out_size, void* d_ws, size_t ws_size,
                              hipStream_t stream) {
  const float* dec  = (const float*)d_in[0];
  const float* enc  = (const float*)d_in[1];
  const float* cov  = (const float*)d_in[2];
  const float* Wq   = (const float*)d_in[3];
  const float* bq   = (const float*)d_in[4];
  const float* Wc   = (const float*)d_in[5];
  const float* v    = (const float*)d_in[6];
  const float* Wo   = (const float*)d_in[7];
  const float* bo   = (const float*)d_in[8];
  const float* wcov = (const float*)d_in[9];

  float* out = (float*)d_out;
  float* attn_h    = out;                         // [T,B,H]
  float* align_out = out + (size_t)TT * BB * HH;  // [T,B,S]

  char* w = (char*)d_ws;
  const size_t MB = 1024 * 1024;
  unsigned short* encpb   = (unsigned short*)(w);                      // 4 MB
  unsigned short* WqT     = (unsigned short*)(w + 4 * MB);             // 0.5 MB
  unsigned short* WcT     = (unsigned short*)(w + 4 * MB + 512 * 1024);// 0.5 MB
  unsigned short* WoT     = (unsigned short*)(w + 5 * MB);             // 1 MB [n][1024]
  unsigned short* concatb = (unsigned short*)(w + 6 * MB);             // 1 MB [b*64+t][1024]
  float*          Ea1     = (float*)(w + 7 * MB);                      // 1 MB
  unsigned short* Ea2b    = (unsigned short*)(w + 8 * MB);             // 4 MB bf16

  k_prep<<<3328, 256, 0, stream>>>(enc, cov, wcov, dec, Wq, Wc, Wo,
                                   encpb, concatb, WqT, WcT, WoT);
  k_gemm12<<<640, 256, 0, stream>>>(concatb, encpb, WqT, WcT, WoT, bq, bo,
                                    Ea1, Ea2b, attn_h);
  k_attn<<<256, 1024, 0, stream>>>(Ea1, Ea2b, v, encpb, align_out, concatb);
  k_out<<<256, 256, 0, stream>>>(concatb, WoT, attn_h);
}

// Round 6
// 125.005 us; speedup vs baseline: 2.2616x; 1.0103x over previous
//
#include <hip/hip_runtime.h>
#include <cstddef>

static constexpr int TT = 64;    // decoder steps
static constexpr int BB = 8;     // batch
static constexpr int SS = 512;   // source length
static constexpr int HH = 512;   // hidden

typedef __attribute__((ext_vector_type(8))) short bf16x8;
typedef __attribute__((ext_vector_type(4))) float f32x4;
typedef __attribute__((ext_vector_type(2))) float f32x2;

__device__ __forceinline__ float fast_tanh(float x) {
  float e = __expf(2.0f * x);
  return 1.0f - 2.0f * __builtin_amdgcn_rcpf(e + 1.0f);
}
__device__ __forceinline__ unsigned short f2bf(float f) {
  unsigned u = __float_as_uint(f);
  return (unsigned short)((u + 0x7FFFu + ((u >> 16) & 1u)) >> 16);   // RNE
}
__device__ __forceinline__ float bflo(unsigned u) { return __uint_as_float(u << 16); }
__device__ __forceinline__ float bfhi(unsigned u) { return __uint_as_float(u & 0xffff0000u); }
__device__ __forceinline__ f32x2 b2(float s) { return (f32x2){s, s}; }
__device__ __forceinline__ f32x2 fma2(f32x2 a, f32x2 b, f32x2 c) {
  return __builtin_elementwise_fma(a, b, c);   // -> v_pk_fma_f32 on gfx950
}

// ---------------------------------------------------------------------------
// k_prep — all preprocessing, vectorized (float4/ushort4):
//  [0,2048):     encpb = bf16(tanh(enc + cov*wcov)), 2 bs-rows/block
//  [2048,2304):  dec pack -> concatb right half, 2 m-rows/block
//  [2304,3328):  weight transposes Wq,Wc,Wo (32x32 tiles -> WT[n][k] bf16)
// ---------------------------------------------------------------------------
__global__ __launch_bounds__(256)
void k_prep(const float* __restrict__ enc, const float* __restrict__ cov,
            const float* __restrict__ wcov, const float* __restrict__ dec,
            const float* __restrict__ Wq, const float* __restrict__ Wc,
            const float* __restrict__ Wo,
            unsigned short* __restrict__ encpb, unsigned short* __restrict__ concatb,
            unsigned short* __restrict__ WqT, unsigned short* __restrict__ WcT,
            unsigned short* __restrict__ WoT) {
  __shared__ float tile[32][33];
  const int blk = blockIdx.x, tid = threadIdx.x;

  if (blk < 2048) {
    const int r = tid >> 7, c = (tid & 127) * 4;
    const int bs = blk * 2 + r;
    const int s = bs & 511, b = bs >> 9;
    const float4 ev = *(const float4*)(enc + (size_t)(s * BB + b) * HH + c);
    const float cv = cov[bs];
    const float4 wv = *(const float4*)(wcov + c);
    ushort4 o;
    o.x = f2bf(fast_tanh(ev.x + cv * wv.x));
    o.y = f2bf(fast_tanh(ev.y + cv * wv.y));
    o.z = f2bf(fast_tanh(ev.z + cv * wv.z));
    o.w = f2bf(fast_tanh(ev.w + cv * wv.w));
    *(ushort4*)(encpb + (size_t)bs * HH + c) = o;
  } else if (blk < 2304) {
    const int r = tid >> 7, c = (tid & 127) * 4;
    const int m = (blk - 2048) * 2 + r, t = m & 63, b = m >> 6;   // m = b*64+t
    const float4 dv = *(const float4*)(dec + (size_t)(t * BB + b) * HH + c);
    ushort4 o;
    o.x = f2bf(dv.x); o.y = f2bf(dv.y); o.z = f2bf(dv.z); o.w = f2bf(dv.w);
    *(ushort4*)(concatb + (size_t)m * 1024 + 512 + c) = o;
  } else {
    int l = blk - 2304;
    const float* W; unsigned short* WT; int KT;
    if (l < 256)      { W = Wq; WT = WqT; KT = 512; }
    else if (l < 512) { W = Wc; WT = WcT; KT = 512; l -= 256; }
    else              { W = Wo; WT = WoT; KT = 1024; l -= 512; }
    const int n0 = (l & 15) * 32, k0 = (l >> 4) * 32;
    const int r = tid >> 3, c4 = (tid & 7) * 4;
    const float4 w = *(const float4*)(W + (size_t)(k0 + r) * 512 + n0 + c4);
    tile[r][c4 + 0] = w.x; tile[r][c4 + 1] = w.y;
    tile[r][c4 + 2] = w.z; tile[r][c4 + 3] = w.w;
    __syncthreads();
    unsigned short* o = WT + (size_t)(n0 + r) * KT + k0 + c4;
#pragma unroll
    for (int i = 0; i < 4; ++i) o[i] = f2bf(tile[c4 + i][r]);
  }
}

// ---------------------------------------------------------------------------
// 64x64 bf16 MFMA tile over K range. 256 thr / 4 waves.
// C/D layout: col=lane&15, row=(lane>>4)*4+reg (verified earlier).
// ---------------------------------------------------------------------------
template<int LDA, int LDB>
__device__ __forceinline__ void gemm_tile(const unsigned short* __restrict__ A,
                                          const unsigned short* __restrict__ BT,
                                          int m0, int n0, int kbeg, int kend,
                                          unsigned short (*As)[72],
                                          unsigned short (*Bs)[72],
                                          f32x4 acc[4]) {
  const int tid = threadIdx.x, w = tid >> 6, lane = tid & 63;
  const int lr = tid >> 2, lk = (tid & 3) * 16;
  const int fm = w * 16 + (lane & 15), fk = (lane >> 4) * 8;
  for (int k0 = kbeg; k0 < kend; k0 += 64) {
    const uint4* ga = (const uint4*)(A + (size_t)(m0 + lr) * LDA + k0 + lk);
    const uint4* gb = (const uint4*)(BT + (size_t)(n0 + lr) * LDB + k0 + lk);
    uint4 a0 = ga[0], a1 = ga[1], b0 = gb[0], b1 = gb[1];
    *(uint4*)&As[lr][lk] = a0;  *(uint4*)&As[lr][lk + 8] = a1;
    *(uint4*)&Bs[lr][lk] = b0;  *(uint4*)&Bs[lr][lk + 8] = b1;
    __syncthreads();
#pragma unroll
    for (int ks = 0; ks < 2; ++ks) {
      bf16x8 af = *(const bf16x8*)&As[fm][ks * 32 + fk];
#pragma unroll
      for (int j = 0; j < 4; ++j) {
        bf16x8 bf = *(const bf16x8*)&Bs[j * 16 + (lane & 15)][ks * 32 + fk];
        acc[j] = __builtin_amdgcn_mfma_f32_16x16x32_bf16(af, bf, acc[j], 0, 0, 0);
      }
    }
    __syncthreads();
  }
}

// ---------------------------------------------------------------------------
// k_gemm12 — three GEMM jobs in ONE launch (640 blocks):
//  g <  64: Ea1 (fp32) = exp(2*clamp(dec@Wq + bq, +-10.5))
//  g < 576: Ea2b (BF16) = exp(2*clamp(encp@Wc, +-10.5))   <- halves L2 stream
//  g < 640: attn_h base = dec@Wo_bot + bo (scattered [T,B,H]); k_out adds c@Wo_top
// clamp +-10.5: pair-product (Ea1*Ea2+1)^2 <= 2.9e36 finite; tanh(10.5)=1-1.5e-9.
// ---------------------------------------------------------------------------
__global__ __launch_bounds__(256)
void k_gemm12(const unsigned short* __restrict__ concatb,
              const unsigned short* __restrict__ encpb,
              const unsigned short* __restrict__ WqT,
              const unsigned short* __restrict__ WcT,
              const unsigned short* __restrict__ WoT,
              const float* __restrict__ bq, const float* __restrict__ bo,
              float* __restrict__ Ea1, unsigned short* __restrict__ Ea2b,
              float* __restrict__ attn_h) {
  __shared__ unsigned short As[64][72];
  __shared__ unsigned short Bs[64][72];
  const int g = blockIdx.x, tid = threadIdx.x;
  const int w = tid >> 6, lane = tid & 63;
  const int col = lane & 15, rq = lane >> 4;

  if (g < 64) {                        // a1
    const int m0 = (g >> 3) * 64, n0 = (g & 7) * 64;
    f32x4 acc[4] = {};
    gemm_tile<1024, 512>(concatb + 512, WqT, m0, n0, 0, 512, As, Bs, acc);
#pragma unroll
    for (int j = 0; j < 4; ++j) {
      const int n = n0 + j * 16 + col;
      const float bv = bq[n];
#pragma unroll
      for (int r = 0; r < 4; ++r) {
        const int m = m0 + w * 16 + rq * 4 + r;
        float val = fminf(fmaxf(acc[j][r] + bv, -10.5f), 10.5f);
        Ea1[(size_t)m * 512 + n] = __expf(2.0f * val);
      }
    }
  } else if (g < 576) {                // a2 -> bf16
    const int u = g - 64;
    const int m0 = (u >> 3) * 64, n0 = (u & 7) * 64;
    f32x4 acc[4] = {};
    gemm_tile<512, 512>(encpb, WcT, m0, n0, 0, 512, As, Bs, acc);
#pragma unroll
    for (int j = 0; j < 4; ++j) {
      const int n = n0 + j * 16 + col;
#pragma unroll
      for (int r = 0; r < 4; ++r) {
        const int m = m0 + w * 16 + rq * 4 + r;
        float val = fminf(fmaxf(acc[j][r], -10.5f), 10.5f);
        Ea2b[(size_t)m * 512 + n] = f2bf(__expf(2.0f * val));
      }
    }
  } else {                             // attn_h base = dec@Wo_bot + bo
    const int u = g - 576;
    const int m0 = (u >> 3) * 64, n0 = (u & 7) * 64;
    f32x4 acc[4] = {};
    gemm_tile<1024, 1024>(concatb, WoT, m0, n0, 512, 1024, As, Bs, acc);
#pragma unroll
    for (int j = 0; j < 4; ++j) {
      const int n = n0 + j * 16 + col;
      const float bv = bo[n];
#pragma unroll
      for (int r = 0; r < 4; ++r) {
        const int m = m0 + w * 16 + rq * 4 + r;
        const int bi = m >> 6, t = m & 63;
        attn_h[(size_t)(t * BB + bi) * 512 + n] = acc[j][r] + bv;
      }
    }
  }
}

// ---------------------------------------------------------------------------
// k_attn — scores + softmax + context; 256 blocks (b, t-pair), 1024 thr.
// t-pair packing via VOP3P packed fp32 (v_pk_fma_f32, gfx950):
//  - ea1p[h] = (Ea1[t0][h], Ea1[t1][h]) in LDS -> pairs arrive packed from
//    ds_read_b64, so the whole pair-rcp PAIR pipeline runs on f32x2
//    (X1/X2/NN/P/acc all packed; rcp stays scalar per lane).
//  - context: scp[s] = (align_t0, align_t1) packed; 4 pk_fma per s-step
//    replace 8 scalar fma.
// Cuts per-thread VALU ~2.6K -> ~1.7K instrs; math bit-identical per lane.
// Scores (pair-rcp, bf16 Ea2): sc = -(sum_h 2 v_h/(Ea1*Ea2+1)).
// ---------------------------------------------------------------------------
__global__ __launch_bounds__(1024)
void k_attn(const float* __restrict__ Ea1, const unsigned short* __restrict__ Ea2b,
            const float* __restrict__ v, const unsigned short* __restrict__ encpb,
            float* __restrict__ align_out, unsigned short* __restrict__ concatb) {
  __shared__ __align__(16) char smem[40960];
  float (*sc)[512] = (float(*)[512])smem;              // [2][512] raw scores
  f32x2* scp       = (f32x2*)(smem + 4096);            // [512] packed align
  f32x2* ea1p      = (f32x2*)(smem + 8192);            // [512] (scores phase)
  float* v2s       = (float*)(smem + 12288);           // [512] (scores phase)
  float (*red)[8]  = (float(*)[8])(smem + 14336);      // [2][8] (softmax)
  f32x2* part2     = (f32x2*)(smem + 8192);            // [4][8][128] (ctx phase)

  const int g = blockIdx.x, tid = threadIdx.x;
  const int b = g & 7, t0 = (g >> 3) * 2;              // XCD-affine b
  const int wv = tid >> 6, lane = tid & 63;
  const int hq = lane & 3, sl = lane >> 2;

  if (tid < 512) {
    const float ev0 = Ea1[(size_t)(b * TT + t0) * HH + tid];
    const float ev1 = Ea1[(size_t)(b * TT + t0 + 1) * HH + tid];
    ea1p[tid] = (f32x2){ev0, ev1};
  } else {
    v2s[tid - 512] = 2.0f * v[tid - 512];
  }
  __syncthreads();

  // ---- scores: 16 waves x 32 s, one pass; t-packed f32x2 pipeline ----
  const int s0 = wv * 32 + sl;                         // and s0+16
  {
    const unsigned short* e2r0 = Ea2b + (size_t)(b * SS + s0) * HH;
    const unsigned short* e2r1 = e2r0 + (size_t)16 * HH;
    f32x2 acc0 = {0.f, 0.f}, acc1 = {0.f, 0.f};        // (t0,t1) for s0, s0+16
    const f32x2 one = {1.f, 1.f};
#define GRP(A, B, E2a, E2b, Va, Vb, ACC)                                     \
    {                                                                        \
      const f32x2 X1 = fma2(A, b2(E2a), one);                                \
      const f32x2 X2 = fma2(B, b2(E2b), one);                                \
      const f32x2 NN = fma2(b2(Va), X2, b2(Vb) * X1);                        \
      const f32x2 P = X1 * X2;                                               \
      const f32x2 RR = {__builtin_amdgcn_rcpf(P.x),                          \
                        __builtin_amdgcn_rcpf(P.y)};                         \
      ACC = fma2(NN, RR, ACC);                                               \
    }
#pragma unroll 4
    for (int it = 0; it < 16; ++it) {
      const int h = it * 32 + hq * 8;
      const uint4 u0 = *(const uint4*)(e2r0 + h);
      const uint4 u1 = *(const uint4*)(e2r1 + h);
      const float4 va = *(const float4*)&v2s[h];
      const float4 vb = *(const float4*)&v2s[h + 4];
      const float4 p0 = *(const float4*)&ea1p[h];      // pairs h, h+1
      const float4 p1 = *(const float4*)&ea1p[h + 2];
      const float4 p2 = *(const float4*)&ea1p[h + 4];
      const float4 p3 = *(const float4*)&ea1p[h + 6];
      const f32x2 A0 = {p0.x, p0.y}, B0 = {p0.z, p0.w};
      const f32x2 A1 = {p1.x, p1.y}, B1 = {p1.z, p1.w};
      const f32x2 A2 = {p2.x, p2.y}, B2 = {p2.z, p2.w};
      const f32x2 A3 = {p3.x, p3.y}, B3 = {p3.z, p3.w};
      GRP(A0, B0, bflo(u0.x), bfhi(u0.x), va.x, va.y, acc0);
      GRP(A1, B1, bflo(u0.y), bfhi(u0.y), va.z, va.w, acc0);
      GRP(A2, B2, bflo(u0.z), bfhi(u0.z), vb.x, vb.y, acc0);
      GRP(A3, B3, bflo(u0.w), bfhi(u0.w), vb.z, vb.w, acc0);
      GRP(A0, B0, bflo(u1.x), bfhi(u1.x), va.x, va.y, acc1);
      GRP(A1, B1, bflo(u1.y), bfhi(u1.y), va.z, va.w, acc1);
      GRP(A2, B2, bflo(u1.z), bfhi(u1.z), vb.x, vb.y, acc1);
      GRP(A3, B3, bflo(u1.w), bfhi(u1.w), vb.z, vb.w, acc1);
    }
#undef GRP
    float a00 = acc0.x, a10 = acc0.y;                  // (t, s0)
    float a01 = acc1.x, a11 = acc1.y;                  // (t, s0+16)
    a00 += __shfl_xor(a00, 1); a00 += __shfl_xor(a00, 2);
    a10 += __shfl_xor(a10, 1); a10 += __shfl_xor(a10, 2);
    a01 += __shfl_xor(a01, 1); a01 += __shfl_xor(a01, 2);
    a11 += __shfl_xor(a11, 1); a11 += __shfl_xor(a11, 2);
    if (hq == 0) {
      sc[0][s0] = -a00; sc[0][s0 + 16] = -a01;
      sc[1][s0] = -a10; sc[1][s0 + 16] = -a11;
    }
  }
  __syncthreads();

  // ---- softmax over s (threads < 512 own s=tid; all threads hit barriers) --
  float x0 = 0.f, x1 = 0.f, e0 = 0.f, e1 = 0.f;
  if (tid < 512) {
    x0 = sc[0][tid]; x1 = sc[1][tid];
    float m0 = x0, m1 = x1;
#pragma unroll
    for (int off = 32; off; off >>= 1) {
      m0 = fmaxf(m0, __shfl_xor(m0, off));
      m1 = fmaxf(m1, __shfl_xor(m1, off));
    }
    if (lane == 0) { red[0][wv] = m0; red[1][wv] = m1; }
  }
  __syncthreads();
  {
    float m0 = red[0][0], m1 = red[1][0];
#pragma unroll
    for (int w2 = 1; w2 < 8; ++w2) { m0 = fmaxf(m0, red[0][w2]); m1 = fmaxf(m1, red[1][w2]); }
    __syncthreads();
    if (tid < 512) {
      e0 = __expf(x0 - m0); e1 = __expf(x1 - m1);
      float s0v = e0, s1v = e1;
#pragma unroll
      for (int off = 32; off; off >>= 1) {
        s0v += __shfl_xor(s0v, off);
        s1v += __shfl_xor(s1v, off);
      }
      if (lane == 0) { red[0][wv] = s0v; red[1][wv] = s1v; }
    }
  }
  __syncthreads();
  {
    float sum0 = 0.f, sum1 = 0.f;
#pragma unroll
    for (int w2 = 0; w2 < 8; ++w2) { sum0 += red[0][w2]; sum1 += red[1][w2]; }
    if (tid < 512) {
      const float a0 = e0 * __builtin_amdgcn_rcpf(sum0);
      const float a1 = e1 * __builtin_amdgcn_rcpf(sum1);
      align_out[(size_t)(t0 + 0) * BB * SS + b * SS + tid] = a0;
      align_out[(size_t)(t0 + 1) * BB * SS + b * SS + tid] = a1;
      scp[tid] = (f32x2){a0, a1};
    }
  }
  __syncthreads();

  // ---- context: q = s-octant (tid>>7), hp2 = h-quad (tid&127); t-packed ----
  {
    const int q = tid >> 7, hp2 = tid & 127;
    const uint2* ep2 = (const uint2*)encpb + (size_t)b * SS * 128;
    f32x2 c0 = {0.f, 0.f}, c1 = {0.f, 0.f}, c2 = {0.f, 0.f}, c3 = {0.f, 0.f};
    const int sbeg = q * 64;
#pragma unroll 8
    for (int s2 = sbeg; s2 < sbeg + 64; ++s2) {
      const uint2 u = ep2[(size_t)s2 * 128 + hp2];
      const f32x2 AV = scp[s2];
      c0 = fma2(AV, b2(bflo(u.x)), c0);
      c1 = fma2(AV, b2(bfhi(u.x)), c1);
      c2 = fma2(AV, b2(bflo(u.y)), c2);
      c3 = fma2(AV, b2(bfhi(u.y)), c3);
    }
    // layout [k][q][hp2] -> conflict-free writes and reads
    part2[0 * 1024 + q * 128 + hp2] = c0;
    part2[1 * 1024 + q * 128 + hp2] = c1;
    part2[2 * 1024 + q * 128 + hp2] = c2;
    part2[3 * 1024 + q * 128 + hp2] = c3;
  }
  __syncthreads();
  if (tid < 128) {
    f32x2 s0_ = {0.f, 0.f}, s1_ = {0.f, 0.f}, s2_ = {0.f, 0.f}, s3_ = {0.f, 0.f};
#pragma unroll
    for (int q2 = 0; q2 < 8; ++q2) {
      s0_ += part2[0 * 1024 + q2 * 128 + tid];
      s1_ += part2[1 * 1024 + q2 * 128 + tid];
      s2_ += part2[2 * 1024 + q2 * 128 + tid];
      s3_ += part2[3 * 1024 + q2 * 128 + tid];
    }
    uint2 o0, o1;
    o0.x = (unsigned)f2bf(s0_.x) | ((unsigned)f2bf(s1_.x) << 16);
    o0.y = (unsigned)f2bf(s2_.x) | ((unsigned)f2bf(s3_.x) << 16);
    o1.x = (unsigned)f2bf(s0_.y) | ((unsigned)f2bf(s1_.y) << 16);
    o1.y = (unsigned)f2bf(s2_.y) | ((unsigned)f2bf(s3_.y) << 16);
    ((uint2*)concatb)[(size_t)(b * TT + t0 + 0) * 256 + tid] = o0;
    ((uint2*)concatb)[(size_t)(b * TT + t0 + 1) * 256 + tid] = o1;
  }
}

// ---------------------------------------------------------------------------
// k_out — attn_h += c@Wo_top (K=512), split-K x4 via HW fp32 atomics on the
// base (dec@Wo_bot + bo) written by k_gemm12. 256 blocks.
// ---------------------------------------------------------------------------
__global__ __launch_bounds__(256)
void k_out(const unsigned short* __restrict__ A,
           const unsigned short* __restrict__ BT,
           float* __restrict__ C) {
  __shared__ unsigned short As[64][72];
  __shared__ unsigned short Bs[64][72];
  const int tid = threadIdx.x;
  const int w = tid >> 6, lane = tid & 63;
  const int tau = blockIdx.x >> 2, kc = blockIdx.x & 3;
  const int n0 = (tau & 7) * 64, m0 = (tau >> 3) * 64;

  f32x4 acc[4] = {};
  gemm_tile<1024, 1024>(A, BT, m0, n0, kc * 128, kc * 128 + 128, As, Bs, acc);

  const int col = lane & 15, rq = lane >> 4;
#pragma unroll
  for (int j = 0; j < 4; ++j) {
    const int n = n0 + j * 16 + col;
#pragma unroll
    for (int r = 0; r < 4; ++r) {
      const int m = m0 + w * 16 + rq * 4 + r;
      const int bi = m >> 6, t = m & 63;
      unsafeAtomicAdd(&C[(size_t)(t * BB + bi) * 512 + n], acc[j][r]);
    }
  }
}

// ---------------------------------------------------------------------------
extern "C" void kernel_launch(void* const* d_in, const int* in_sizes, int n_in,
                              void* d_out, int out_size, void* d_ws, size_t ws_size,
                              hipStream_t stream) {
  const float* dec  = (const float*)d_in[0];
  const float* enc  = (const float*)d_in[1];
  const float* cov  = (const float*)d_in[2];
  const float* Wq   = (const float*)d_in[3];
  const float* bq   = (const float*)d_in[4];
  const float* Wc   = (const float*)d_in[5];
  const float* v    = (const float*)d_in[6];
  const float* Wo   = (const float*)d_in[7];
  const float* bo   = (const float*)d_in[8];
  const float* wcov = (const float*)d_in[9];

  float* out = (float*)d_out;
  float* attn_h    = out;                         // [T,B,H]
  float* align_out = out + (size_t)TT * BB * HH;  // [T,B,S]

  char* w = (char*)d_ws;
  const size_t MB = 1024 * 1024;
  unsigned short* encpb   = (unsigned short*)(w);                      // 4 MB
  unsigned short* WqT     = (unsigned short*)(w + 4 * MB);             // 0.5 MB
  unsigned short* WcT     = (unsigned short*)(w + 4 * MB + 512 * 1024);// 0.5 MB
  unsigned short* WoT     = (unsigned short*)(w + 5 * MB);             // 1 MB [n][1024]
  unsigned short* concatb = (unsigned short*)(w + 6 * MB);             // 1 MB [b*64+t][1024]
  float*          Ea1     = (float*)(w + 7 * MB);                      // 1 MB
  unsigned short* Ea2b    = (unsigned short*)(w + 8 * MB);             // 4 MB bf16

  k_prep<<<3328, 256, 0, stream>>>(enc, cov, wcov, dec, Wq, Wc, Wo,
                                   encpb, concatb, WqT, WcT, WoT);
  k_gemm12<<<640, 256, 0, stream>>>(concatb, encpb, WqT, WcT, WoT, bq, bo,
                                    Ea1, Ea2b, attn_h);
  k_attn<<<256, 1024, 0, stream>>>(Ea1, Ea2b, v, encpb, align_out, concatb);
  k_out<<<256, 256, 0, stream>>>(concatb, WoT, attn_h);
}

// Round 7
// 123.145 us; speedup vs baseline: 2.2958x; 1.0151x over previous
//
#include <hip/hip_runtime.h>
#include <cstddef>

static constexpr int TT = 64;    // decoder steps
static constexpr int BB = 8;     // batch
static constexpr int SS = 512;   // source length
static constexpr int HH = 512;   // hidden

typedef __attribute__((ext_vector_type(8))) short bf16x8;
typedef __attribute__((ext_vector_type(4))) float f32x4;
typedef __attribute__((ext_vector_type(2))) float f32x2;

__device__ __forceinline__ float fast_tanh(float x) {
  float e = __expf(2.0f * x);
  return 1.0f - 2.0f * __builtin_amdgcn_rcpf(e + 1.0f);
}
__device__ __forceinline__ unsigned short f2bf(float f) {
  unsigned u = __float_as_uint(f);
  return (unsigned short)((u + 0x7FFFu + ((u >> 16) & 1u)) >> 16);   // RNE
}
__device__ __forceinline__ float bflo(unsigned u) { return __uint_as_float(u << 16); }
__device__ __forceinline__ float bfhi(unsigned u) { return __uint_as_float(u & 0xffff0000u); }
__device__ __forceinline__ f32x2 b2(float s) { return (f32x2){s, s}; }
__device__ __forceinline__ f32x2 fma2(f32x2 a, f32x2 b, f32x2 c) {
  return __builtin_elementwise_fma(a, b, c);   // -> v_pk_fma_f32 on gfx950
}

// ---------------------------------------------------------------------------
// k_prep — all preprocessing, consolidated to 1088 blocks so the whole grid
// is resident in ONE scheduling round (3328 blocks = 852K threads exceeded
// the 524K device thread capacity -> 2 rounds + tail):
//  [0,512):     encpb = bf16(tanh(enc + cov*wcov)), 8 bs-rows/block
//  [512,576):   dec pack -> concatb right half, 8 m-rows/block
//  [576,1088):  weight transposes Wq,Wc,Wo, 2 32x32 tiles/block
// ---------------------------------------------------------------------------
__global__ __launch_bounds__(256)
void k_prep(const float* __restrict__ enc, const float* __restrict__ cov,
            const float* __restrict__ wcov, const float* __restrict__ dec,
            const float* __restrict__ Wq, const float* __restrict__ Wc,
            const float* __restrict__ Wo,
            unsigned short* __restrict__ encpb, unsigned short* __restrict__ concatb,
            unsigned short* __restrict__ WqT, unsigned short* __restrict__ WcT,
            unsigned short* __restrict__ WoT) {
  __shared__ float tile[32][33];
  const int blk = blockIdx.x, tid = threadIdx.x;

  if (blk < 512) {
    const int r = tid >> 7, c = (tid & 127) * 4;
    const float4 wv = *(const float4*)(wcov + c);
#pragma unroll
    for (int rep = 0; rep < 4; ++rep) {
      const int bs = blk * 8 + rep * 2 + r;
      const int s = bs & 511, b = bs >> 9;
      const float4 ev = *(const float4*)(enc + (size_t)(s * BB + b) * HH + c);
      const float cv = cov[bs];
      ushort4 o;
      o.x = f2bf(fast_tanh(ev.x + cv * wv.x));
      o.y = f2bf(fast_tanh(ev.y + cv * wv.y));
      o.z = f2bf(fast_tanh(ev.z + cv * wv.z));
      o.w = f2bf(fast_tanh(ev.w + cv * wv.w));
      *(ushort4*)(encpb + (size_t)bs * HH + c) = o;
    }
  } else if (blk < 576) {
    const int r = tid >> 7, c = (tid & 127) * 4;
#pragma unroll
    for (int rep = 0; rep < 4; ++rep) {
      const int m = (blk - 512) * 8 + rep * 2 + r;
      const int t = m & 63, b = m >> 6;              // m = b*64+t
      const float4 dv = *(const float4*)(dec + (size_t)(t * BB + b) * HH + c);
      ushort4 o;
      o.x = f2bf(dv.x); o.y = f2bf(dv.y); o.z = f2bf(dv.z); o.w = f2bf(dv.w);
      *(ushort4*)(concatb + (size_t)m * 1024 + 512 + c) = o;
    }
  } else {
    const int r = tid >> 3, c4 = (tid & 7) * 4;
#pragma unroll
    for (int it = 0; it < 2; ++it) {
      int l = (blk - 576) * 2 + it;
      const float* W; unsigned short* WT; int KT;
      if (l < 256)      { W = Wq; WT = WqT; KT = 512; }
      else if (l < 512) { W = Wc; WT = WcT; KT = 512; l -= 256; }
      else              { W = Wo; WT = WoT; KT = 1024; l -= 512; }
      const int n0 = (l & 15) * 32, k0 = (l >> 4) * 32;
      const float4 w = *(const float4*)(W + (size_t)(k0 + r) * 512 + n0 + c4);
      tile[r][c4 + 0] = w.x; tile[r][c4 + 1] = w.y;
      tile[r][c4 + 2] = w.z; tile[r][c4 + 3] = w.w;
      __syncthreads();
      unsigned short* o = WT + (size_t)(n0 + r) * KT + k0 + c4;
#pragma unroll
      for (int i = 0; i < 4; ++i) o[i] = f2bf(tile[c4 + i][r]);
      __syncthreads();
    }
  }
}

// ---------------------------------------------------------------------------
// 64x64 bf16 MFMA tile over K range. 256 thr / 4 waves.
// C/D layout: col=lane&15, row=(lane>>4)*4+reg (verified earlier).
// ---------------------------------------------------------------------------
template<int LDA, int LDB>
__device__ __forceinline__ void gemm_tile(const unsigned short* __restrict__ A,
                                          const unsigned short* __restrict__ BT,
                                          int m0, int n0, int kbeg, int kend,
                                          unsigned short (*As)[72],
                                          unsigned short (*Bs)[72],
                                          f32x4 acc[4]) {
  const int tid = threadIdx.x, w = tid >> 6, lane = tid & 63;
  const int lr = tid >> 2, lk = (tid & 3) * 16;
  const int fm = w * 16 + (lane & 15), fk = (lane >> 4) * 8;
  for (int k0 = kbeg; k0 < kend; k0 += 64) {
    const uint4* ga = (const uint4*)(A + (size_t)(m0 + lr) * LDA + k0 + lk);
    const uint4* gb = (const uint4*)(BT + (size_t)(n0 + lr) * LDB + k0 + lk);
    uint4 a0 = ga[0], a1 = ga[1], b0 = gb[0], b1 = gb[1];
    *(uint4*)&As[lr][lk] = a0;  *(uint4*)&As[lr][lk + 8] = a1;
    *(uint4*)&Bs[lr][lk] = b0;  *(uint4*)&Bs[lr][lk + 8] = b1;
    __syncthreads();
#pragma unroll
    for (int ks = 0; ks < 2; ++ks) {
      bf16x8 af = *(const bf16x8*)&As[fm][ks * 32 + fk];
#pragma unroll
      for (int j = 0; j < 4; ++j) {
        bf16x8 bf = *(const bf16x8*)&Bs[j * 16 + (lane & 15)][ks * 32 + fk];
        acc[j] = __builtin_amdgcn_mfma_f32_16x16x32_bf16(af, bf, acc[j], 0, 0, 0);
      }
    }
    __syncthreads();
  }
}

// ---------------------------------------------------------------------------
// k_gemm12 — three GEMM jobs in ONE launch (640 blocks):
//  g <  64: Ea1 (fp32) = exp(2*clamp(dec@Wq + bq, +-10.5))
//  g < 576: Ea2b (BF16) = exp(2*clamp(encp@Wc, +-10.5))   <- halves L2 stream
//  g < 640: attn_h base = dec@Wo_bot + bo (scattered [T,B,H]); k_out adds c@Wo_top
// clamp +-10.5: pair-product (Ea1*Ea2+1)^2 <= 2.9e36 finite; tanh(10.5)=1-1.5e-9.
// ---------------------------------------------------------------------------
__global__ __launch_bounds__(256)
void k_gemm12(const unsigned short* __restrict__ concatb,
              const unsigned short* __restrict__ encpb,
              const unsigned short* __restrict__ WqT,
              const unsigned short* __restrict__ WcT,
              const unsigned short* __restrict__ WoT,
              const float* __restrict__ bq, const float* __restrict__ bo,
              float* __restrict__ Ea1, unsigned short* __restrict__ Ea2b,
              float* __restrict__ attn_h) {
  __shared__ unsigned short As[64][72];
  __shared__ unsigned short Bs[64][72];
  const int g = blockIdx.x, tid = threadIdx.x;
  const int w = tid >> 6, lane = tid & 63;
  const int col = lane & 15, rq = lane >> 4;

  if (g < 64) {                        // a1
    const int m0 = (g >> 3) * 64, n0 = (g & 7) * 64;
    f32x4 acc[4] = {};
    gemm_tile<1024, 512>(concatb + 512, WqT, m0, n0, 0, 512, As, Bs, acc);
#pragma unroll
    for (int j = 0; j < 4; ++j) {
      const int n = n0 + j * 16 + col;
      const float bv = bq[n];
#pragma unroll
      for (int r = 0; r < 4; ++r) {
        const int m = m0 + w * 16 + rq * 4 + r;
        float val = fminf(fmaxf(acc[j][r] + bv, -10.5f), 10.5f);
        Ea1[(size_t)m * 512 + n] = __expf(2.0f * val);
      }
    }
  } else if (g < 576) {                // a2 -> bf16
    const int u = g - 64;
    const int m0 = (u >> 3) * 64, n0 = (u & 7) * 64;
    f32x4 acc[4] = {};
    gemm_tile<512, 512>(encpb, WcT, m0, n0, 0, 512, As, Bs, acc);
#pragma unroll
    for (int j = 0; j < 4; ++j) {
      const int n = n0 + j * 16 + col;
#pragma unroll
      for (int r = 0; r < 4; ++r) {
        const int m = m0 + w * 16 + rq * 4 + r;
        float val = fminf(fmaxf(acc[j][r], -10.5f), 10.5f);
        Ea2b[(size_t)m * 512 + n] = f2bf(__expf(2.0f * val));
      }
    }
  } else {                             // attn_h base = dec@Wo_bot + bo
    const int u = g - 576;
    const int m0 = (u >> 3) * 64, n0 = (u & 7) * 64;
    f32x4 acc[4] = {};
    gemm_tile<1024, 1024>(concatb, WoT, m0, n0, 512, 1024, As, Bs, acc);
#pragma unroll
    for (int j = 0; j < 4; ++j) {
      const int n = n0 + j * 16 + col;
      const float bv = bo[n];
#pragma unroll
      for (int r = 0; r < 4; ++r) {
        const int m = m0 + w * 16 + rq * 4 + r;
        const int bi = m >> 6, t = m & 63;
        attn_h[(size_t)(t * BB + bi) * 512 + n] = acc[j][r] + bv;
      }
    }
  }
}

// ---------------------------------------------------------------------------
// k_attn — scores + softmax + context; 256 blocks (b, t-pair), 1024 thr.
// Structural optimum (established r0-r6): t-pair x 1024thr is the granularity-
// constrained minimum L2 traffic (t-single doubles traffic +8us [r4]; t-quad
// needs 512-thr blocks -> half the CUs idle). Packed f32x2 pipeline [r6].
// Scores (pair-rcp, bf16 Ea2): sc = -(sum_h 2 v_h/(Ea1*Ea2+1)).
// ---------------------------------------------------------------------------
__global__ __launch_bounds__(1024)
void k_attn(const float* __restrict__ Ea1, const unsigned short* __restrict__ Ea2b,
            const float* __restrict__ v, const unsigned short* __restrict__ encpb,
            float* __restrict__ align_out, unsigned short* __restrict__ concatb) {
  __shared__ __align__(16) char smem[40960];
  float (*sc)[512] = (float(*)[512])smem;              // [2][512] raw scores
  f32x2* scp       = (f32x2*)(smem + 4096);            // [512] packed align
  f32x2* ea1p      = (f32x2*)(smem + 8192);            // [512] (scores phase)
  float* v2s       = (float*)(smem + 12288);           // [512] (scores phase)
  float (*red)[8]  = (float(*)[8])(smem + 14336);      // [2][8] (softmax)
  f32x2* part2     = (f32x2*)(smem + 8192);            // [4][8][128] (ctx phase)

  const int g = blockIdx.x, tid = threadIdx.x;
  const int b = g & 7, t0 = (g >> 3) * 2;              // XCD-affine b
  const int wv = tid >> 6, lane = tid & 63;
  const int hq = lane & 3, sl = lane >> 2;

  if (tid < 512) {
    const float ev0 = Ea1[(size_t)(b * TT + t0) * HH + tid];
    const float ev1 = Ea1[(size_t)(b * TT + t0 + 1) * HH + tid];
    ea1p[tid] = (f32x2){ev0, ev1};
  } else {
    v2s[tid - 512] = 2.0f * v[tid - 512];
  }
  __syncthreads();

  // ---- scores: 16 waves x 32 s, one pass; t-packed f32x2 pipeline ----
  const int s0 = wv * 32 + sl;                         // and s0+16
  {
    const unsigned short* e2r0 = Ea2b + (size_t)(b * SS + s0) * HH;
    const unsigned short* e2r1 = e2r0 + (size_t)16 * HH;
    f32x2 acc0 = {0.f, 0.f}, acc1 = {0.f, 0.f};        // (t0,t1) for s0, s0+16
    const f32x2 one = {1.f, 1.f};
#define GRP(A, B, E2a, E2b, Va, Vb, ACC)                                     \
    {                                                                        \
      const f32x2 X1 = fma2(A, b2(E2a), one);                                \
      const f32x2 X2 = fma2(B, b2(E2b), one);                                \
      const f32x2 NN = fma2(b2(Va), X2, b2(Vb) * X1);                        \
      const f32x2 P = X1 * X2;                                               \
      const f32x2 RR = {__builtin_amdgcn_rcpf(P.x),                          \
                        __builtin_amdgcn_rcpf(P.y)};                         \
      ACC = fma2(NN, RR, ACC);                                               \
    }
#pragma unroll 4
    for (int it = 0; it < 16; ++it) {
      const int h = it * 32 + hq * 8;
      const uint4 u0 = *(const uint4*)(e2r0 + h);
      const uint4 u1 = *(const uint4*)(e2r1 + h);
      const float4 va = *(const float4*)&v2s[h];
      const float4 vb = *(const float4*)&v2s[h + 4];
      const float4 p0 = *(const float4*)&ea1p[h];      // pairs h, h+1
      const float4 p1 = *(const float4*)&ea1p[h + 2];
      const float4 p2 = *(const float4*)&ea1p[h + 4];
      const float4 p3 = *(const float4*)&ea1p[h + 6];
      const f32x2 A0 = {p0.x, p0.y}, B0 = {p0.z, p0.w};
      const f32x2 A1 = {p1.x, p1.y}, B1 = {p1.z, p1.w};
      const f32x2 A2 = {p2.x, p2.y}, B2 = {p2.z, p2.w};
      const f32x2 A3 = {p3.x, p3.y}, B3 = {p3.z, p3.w};
      GRP(A0, B0, bflo(u0.x), bfhi(u0.x), va.x, va.y, acc0);
      GRP(A1, B1, bflo(u0.y), bfhi(u0.y), va.z, va.w, acc0);
      GRP(A2, B2, bflo(u0.z), bfhi(u0.z), vb.x, vb.y, acc0);
      GRP(A3, B3, bflo(u0.w), bfhi(u0.w), vb.z, vb.w, acc0);
      GRP(A0, B0, bflo(u1.x), bfhi(u1.x), va.x, va.y, acc1);
      GRP(A1, B1, bflo(u1.y), bfhi(u1.y), va.z, va.w, acc1);
      GRP(A2, B2, bflo(u1.z), bfhi(u1.z), vb.x, vb.y, acc1);
      GRP(A3, B3, bflo(u1.w), bfhi(u1.w), vb.z, vb.w, acc1);
    }
#undef GRP
    float a00 = acc0.x, a10 = acc0.y;                  // (t, s0)
    float a01 = acc1.x, a11 = acc1.y;                  // (t, s0+16)
    a00 += __shfl_xor(a00, 1); a00 += __shfl_xor(a00, 2);
    a10 += __shfl_xor(a10, 1); a10 += __shfl_xor(a10, 2);
    a01 += __shfl_xor(a01, 1); a01 += __shfl_xor(a01, 2);
    a11 += __shfl_xor(a11, 1); a11 += __shfl_xor(a11, 2);
    if (hq == 0) {
      sc[0][s0] = -a00; sc[0][s0 + 16] = -a01;
      sc[1][s0] = -a10; sc[1][s0 + 16] = -a11;
    }
  }
  __syncthreads();

  // ---- softmax over s (threads < 512 own s=tid; all threads hit barriers) --
  float x0 = 0.f, x1 = 0.f, e0 = 0.f, e1 = 0.f;
  if (tid < 512) {
    x0 = sc[0][tid]; x1 = sc[1][tid];
    float m0 = x0, m1 = x1;
#pragma unroll
    for (int off = 32; off; off >>= 1) {
      m0 = fmaxf(m0, __shfl_xor(m0, off));
      m1 = fmaxf(m1, __shfl_xor(m1, off));
    }
    if (lane == 0) { red[0][wv] = m0; red[1][wv] = m1; }
  }
  __syncthreads();
  {
    float m0 = red[0][0], m1 = red[1][0];
#pragma unroll
    for (int w2 = 1; w2 < 8; ++w2) { m0 = fmaxf(m0, red[0][w2]); m1 = fmaxf(m1, red[1][w2]); }
    __syncthreads();
    if (tid < 512) {
      e0 = __expf(x0 - m0); e1 = __expf(x1 - m1);
      float s0v = e0, s1v = e1;
#pragma unroll
      for (int off = 32; off; off >>= 1) {
        s0v += __shfl_xor(s0v, off);
        s1v += __shfl_xor(s1v, off);
      }
      if (lane == 0) { red[0][wv] = s0v; red[1][wv] = s1v; }
    }
  }
  __syncthreads();
  {
    float sum0 = 0.f, sum1 = 0.f;
#pragma unroll
    for (int w2 = 0; w2 < 8; ++w2) { sum0 += red[0][w2]; sum1 += red[1][w2]; }
    if (tid < 512) {
      const float a0 = e0 * __builtin_amdgcn_rcpf(sum0);
      const float a1 = e1 * __builtin_amdgcn_rcpf(sum1);
      align_out[(size_t)(t0 + 0) * BB * SS + b * SS + tid] = a0;
      align_out[(size_t)(t0 + 1) * BB * SS + b * SS + tid] = a1;
      scp[tid] = (f32x2){a0, a1};
    }
  }
  __syncthreads();

  // ---- context: q = s-octant (tid>>7), hp2 = h-quad (tid&127); t-packed ----
  {
    const int q = tid >> 7, hp2 = tid & 127;
    const uint2* ep2 = (const uint2*)encpb + (size_t)b * SS * 128;
    f32x2 c0 = {0.f, 0.f}, c1 = {0.f, 0.f}, c2 = {0.f, 0.f}, c3 = {0.f, 0.f};
    const int sbeg = q * 64;
#pragma unroll 8
    for (int s2 = sbeg; s2 < sbeg + 64; ++s2) {
      const uint2 u = ep2[(size_t)s2 * 128 + hp2];
      const f32x2 AV = scp[s2];
      c0 = fma2(AV, b2(bflo(u.x)), c0);
      c1 = fma2(AV, b2(bfhi(u.x)), c1);
      c2 = fma2(AV, b2(bflo(u.y)), c2);
      c3 = fma2(AV, b2(bfhi(u.y)), c3);
    }
    // layout [k][q][hp2] -> conflict-free writes and reads
    part2[0 * 1024 + q * 128 + hp2] = c0;
    part2[1 * 1024 + q * 128 + hp2] = c1;
    part2[2 * 1024 + q * 128 + hp2] = c2;
    part2[3 * 1024 + q * 128 + hp2] = c3;
  }
  __syncthreads();
  if (tid < 128) {
    f32x2 s0_ = {0.f, 0.f}, s1_ = {0.f, 0.f}, s2_ = {0.f, 0.f}, s3_ = {0.f, 0.f};
#pragma unroll
    for (int q2 = 0; q2 < 8; ++q2) {
      s0_ += part2[0 * 1024 + q2 * 128 + tid];
      s1_ += part2[1 * 1024 + q2 * 128 + tid];
      s2_ += part2[2 * 1024 + q2 * 128 + tid];
      s3_ += part2[3 * 1024 + q2 * 128 + tid];
    }
    uint2 o0, o1;
    o0.x = (unsigned)f2bf(s0_.x) | ((unsigned)f2bf(s1_.x) << 16);
    o0.y = (unsigned)f2bf(s2_.x) | ((unsigned)f2bf(s3_.x) << 16);
    o1.x = (unsigned)f2bf(s0_.y) | ((unsigned)f2bf(s1_.y) << 16);
    o1.y = (unsigned)f2bf(s2_.y) | ((unsigned)f2bf(s3_.y) << 16);
    ((uint2*)concatb)[(size_t)(b * TT + t0 + 0) * 256 + tid] = o0;
    ((uint2*)concatb)[(size_t)(b * TT + t0 + 1) * 256 + tid] = o1;
  }
}

// ---------------------------------------------------------------------------
// k_out — attn_h += c@Wo_top (K=512), split-K x4 via HW fp32 atomics on the
// base (dec@Wo_bot + bo) written by k_gemm12. 256 blocks.
// ---------------------------------------------------------------------------
__global__ __launch_bounds__(256)
void k_out(const unsigned short* __restrict__ A,
           const unsigned short* __restrict__ BT,
           float* __restrict__ C) {
  __shared__ unsigned short As[64][72];
  __shared__ unsigned short Bs[64][72];
  const int tid = threadIdx.x;
  const int w = tid >> 6, lane = tid & 63;
  const int tau = blockIdx.x >> 2, kc = blockIdx.x & 3;
  const int n0 = (tau & 7) * 64, m0 = (tau >> 3) * 64;

  f32x4 acc[4] = {};
  gemm_tile<1024, 1024>(A, BT, m0, n0, kc * 128, kc * 128 + 128, As, Bs, acc);

  const int col = lane & 15, rq = lane >> 4;
#pragma unroll
  for (int j = 0; j < 4; ++j) {
    const int n = n0 + j * 16 + col;
#pragma unroll
    for (int r = 0; r < 4; ++r) {
      const int m = m0 + w * 16 + rq * 4 + r;
      const int bi = m >> 6, t = m & 63;
      unsafeAtomicAdd(&C[(size_t)(t * BB + bi) * 512 + n], acc[j][r]);
    }
  }
}

// ---------------------------------------------------------------------------
extern "C" void kernel_launch(void* const* d_in, const int* in_sizes, int n_in,
                              void* d_out, int out_size, void* d_ws, size_t ws_size,
                              hipStream_t stream) {
  const float* dec  = (const float*)d_in[0];
  const float* enc  = (const float*)d_in[1];
  const float* cov  = (const float*)d_in[2];
  const float* Wq   = (const float*)d_in[3];
  const float* bq   = (const float*)d_in[4];
  const float* Wc   = (const float*)d_in[5];
  const float* v    = (const float*)d_in[6];
  const float* Wo   = (const float*)d_in[7];
  const float* bo   = (const float*)d_in[8];
  const float* wcov = (const float*)d_in[9];

  float* out = (float*)d_out;
  float* attn_h    = out;                         // [T,B,H]
  float* align_out = out + (size_t)TT * BB * HH;  // [T,B,S]

  char* w = (char*)d_ws;
  const size_t MB = 1024 * 1024;
  unsigned short* encpb   = (unsigned short*)(w);                      // 4 MB
  unsigned short* WqT     = (unsigned short*)(w + 4 * MB);             // 0.5 MB
  unsigned short* WcT     = (unsigned short*)(w + 4 * MB + 512 * 1024);// 0.5 MB
  unsigned short* WoT     = (unsigned short*)(w + 5 * MB);             // 1 MB [n][1024]
  unsigned short* concatb = (unsigned short*)(w + 6 * MB);             // 1 MB [b*64+t][1024]
  float*          Ea1     = (float*)(w + 7 * MB);                      // 1 MB
  unsigned short* Ea2b    = (unsigned short*)(w + 8 * MB);             // 4 MB bf16

  k_prep<<<1088, 256, 0, stream>>>(enc, cov, wcov, dec, Wq, Wc, Wo,
                                   encpb, concatb, WqT, WcT, WoT);
  k_gemm12<<<640, 256, 0, stream>>>(concatb, encpb, WqT, WcT, WoT, bq, bo,
                                    Ea1, Ea2b, attn_h);
  k_attn<<<256, 1024, 0, stream>>>(Ea1, Ea2b, v, encpb, align_out, concatb);
  k_out<<<256, 256, 0, stream>>>(concatb, WoT, attn_h);
}